// Round 2
// baseline (733.565 us; speedup 1.0000x reference)
//
#include <hip/hip_runtime.h>

// ---------------- preprocessing: degree histogram, scan, CSR scatter ----------------

__global__ void hist_kernel(const int* __restrict__ dst, int E, int* __restrict__ count) {
    int stride = gridDim.x * blockDim.x;
    for (int e = blockIdx.x * blockDim.x + threadIdx.x; e < E; e += stride)
        atomicAdd(&count[dst[e]], 1);
}

__global__ void dinv_kernel(const int* __restrict__ count, float* __restrict__ dinv, int N) {
    int i = blockIdx.x * blockDim.x + threadIdx.x;
    if (i < N) dinv[i] = 1.0f / sqrtf((float)count[i] + 1.0f);
}

// single-block exclusive scan over N counts -> row_ptr[0..N]
__global__ void scan_kernel(const int* __restrict__ count, int* __restrict__ row_ptr, int N) {
    __shared__ int buf[2][1024];
    int t = threadIdx.x;
    int chunk = (N + 1023) >> 10;
    int lo = min(t * chunk, N), hi = min(lo + chunk, N);
    int s = 0;
    for (int i = lo; i < hi; ++i) s += count[i];
    buf[0][t] = s;
    __syncthreads();
    int pi = 0;
    for (int off = 1; off < 1024; off <<= 1) {
        int v = buf[pi][t];
        if (t >= off) v += buf[pi][t - off];
        buf[pi ^ 1][t] = v;
        pi ^= 1;
        __syncthreads();
    }
    int run = (t == 0) ? 0 : buf[pi][t - 1];
    for (int i = lo; i < hi; ++i) { row_ptr[i] = run; run += count[i]; }
    if (lo < N && hi == N) row_ptr[N] = run;
}

__global__ void scatter_kernel(const int* __restrict__ src, const int* __restrict__ dst, int E,
                               const int* __restrict__ row_ptr, int* __restrict__ fill,
                               int* __restrict__ col) {
    int stride = gridDim.x * blockDim.x;
    for (int e = blockIdx.x * blockDim.x + threadIdx.x; e < E; e += stride) {
        int d = dst[e];
        int pos = row_ptr[d] + atomicAdd(&fill[d], 1);
        col[pos] = src[e];
    }
}

// ---------------- fp32 GEMM: Out[M][64] = A[M][K] @ W[K][64] ----------------
// block = 256 threads, tile = 64 rows x 64 cols, K staged in 64-chunks.
// As padded to 68 floats/row -> A-broadcast reads hit 2 banks (free 2-way).
template <int K>
__global__ __launch_bounds__(256, 2) void gemm_kernel(const float* __restrict__ A,
                                                      const float* __restrict__ W,
                                                      float* __restrict__ Out, int M) {
    __shared__ float Ws[K][64];
    __shared__ float As[64][68];
    int t = threadIdx.x;
    for (int i = t * 4; i < K * 64; i += 1024)
        *(float4*)&Ws[i >> 6][i & 63] = *(const float4*)(W + i);

    int row0 = blockIdx.x * 64;
    int rt = (t >> 4) * 4;  // 4 rows per thread
    int ct = (t & 15) * 4;  // 4 cols per thread
    float acc[4][4];
#pragma unroll
    for (int m = 0; m < 4; m++) { acc[m][0] = 0.f; acc[m][1] = 0.f; acc[m][2] = 0.f; acc[m][3] = 0.f; }

    for (int k0 = 0; k0 < K; k0 += 64) {
        __syncthreads();
        for (int i = t * 4; i < 64 * 64; i += 1024) {
            int r = i >> 6, c = i & 63;
            int gr = row0 + r;
            float4 v = make_float4(0.f, 0.f, 0.f, 0.f);
            if (gr < M) v = *(const float4*)(A + (size_t)gr * K + k0 + c);
            *(float4*)&As[r][c] = v;
        }
        __syncthreads();
#pragma unroll
        for (int kk = 0; kk < 64; ++kk) {
            float a0 = As[rt + 0][kk], a1 = As[rt + 1][kk];
            float a2 = As[rt + 2][kk], a3 = As[rt + 3][kk];
            float4 w = *(float4*)&Ws[k0 + kk][ct];
            acc[0][0] += a0 * w.x; acc[0][1] += a0 * w.y; acc[0][2] += a0 * w.z; acc[0][3] += a0 * w.w;
            acc[1][0] += a1 * w.x; acc[1][1] += a1 * w.y; acc[1][2] += a1 * w.z; acc[1][3] += a1 * w.w;
            acc[2][0] += a2 * w.x; acc[2][1] += a2 * w.y; acc[2][2] += a2 * w.z; acc[2][3] += a2 * w.w;
            acc[3][0] += a3 * w.x; acc[3][1] += a3 * w.y; acc[3][2] += a3 * w.z; acc[3][3] += a3 * w.w;
        }
    }
#pragma unroll
    for (int m = 0; m < 4; m++) {
        int gr = row0 + rt + m;
        if (gr < M)
            *(float4*)(Out + (size_t)gr * 64 + ct) =
                make_float4(acc[m][0], acc[m][1], acc[m][2], acc[m][3]);
    }
}

// ---------------- edge aggregation (gather via CSR), one wave per node ----------------
// out_i = dinv_i * ( sum_{e: dst=i} dinv[src_e] * Hin[src_e] + dinv_i * Hin[i] ) + bias

__global__ void agg_relu_kernel(const float* __restrict__ Hin, const int* __restrict__ row_ptr,
                                const int* __restrict__ col, const float* __restrict__ dinv,
                                const float* __restrict__ bias, float* __restrict__ Hout, int N) {
    int gid = blockIdx.x * blockDim.x + threadIdx.x;
    int i = gid >> 6;
    int lane = threadIdx.x & 63;
    if (i >= N) return;
    float di = dinv[i];
    int beg = row_ptr[i], end = row_ptr[i + 1];
    float acc = di * Hin[(size_t)i * 64 + lane];
    int e = beg;
    for (; e + 4 <= end; e += 4) {
        int s0 = col[e], s1 = col[e + 1], s2 = col[e + 2], s3 = col[e + 3];
        float w0 = dinv[s0], w1 = dinv[s1], w2 = dinv[s2], w3 = dinv[s3];
        float v0 = Hin[(size_t)s0 * 64 + lane];
        float v1 = Hin[(size_t)s1 * 64 + lane];
        float v2 = Hin[(size_t)s2 * 64 + lane];
        float v3 = Hin[(size_t)s3 * 64 + lane];
        acc = fmaf(w0, v0, acc); acc = fmaf(w1, v1, acc);
        acc = fmaf(w2, v2, acc); acc = fmaf(w3, v3, acc);
    }
    for (; e < end; ++e) {
        int s = col[e];
        acc = fmaf(dinv[s], Hin[(size_t)s * 64 + lane], acc);
    }
    float r = di * acc + bias[lane];
    Hout[(size_t)i * 64 + lane] = fmaxf(r, 0.f);
}

__global__ void agg_out_kernel(const float* __restrict__ Hin, const int* __restrict__ row_ptr,
                               const int* __restrict__ col, const float* __restrict__ dinv,
                               const float* __restrict__ bm, const float* __restrict__ bl,
                               float* __restrict__ out, int N) {
    int gid = blockIdx.x * blockDim.x + threadIdx.x;
    int i = gid >> 6;
    int lane = threadIdx.x & 63;
    if (i >= N) return;
    float di = dinv[i];
    int beg = row_ptr[i], end = row_ptr[i + 1];
    float acc = di * Hin[(size_t)i * 64 + lane];
    int e = beg;
    for (; e + 4 <= end; e += 4) {
        int s0 = col[e], s1 = col[e + 1], s2 = col[e + 2], s3 = col[e + 3];
        float w0 = dinv[s0], w1 = dinv[s1], w2 = dinv[s2], w3 = dinv[s3];
        float v0 = Hin[(size_t)s0 * 64 + lane];
        float v1 = Hin[(size_t)s1 * 64 + lane];
        float v2 = Hin[(size_t)s2 * 64 + lane];
        float v3 = Hin[(size_t)s3 * 64 + lane];
        acc = fmaf(w0, v0, acc); acc = fmaf(w1, v1, acc);
        acc = fmaf(w2, v2, acc); acc = fmaf(w3, v3, acc);
    }
    for (; e < end; ++e) {
        int s = col[e];
        acc = fmaf(dinv[s], Hin[(size_t)s * 64 + lane], acc);
    }
    float r;
    if (lane < 32) {
        r = di * acc + bm[lane];
        out[(size_t)i * 32 + lane] = r;
    } else {
        r = di * acc + bl[lane - 32];
        out[(size_t)(N + i) * 32 + (lane - 32)] = r;
    }
}

// concat Wm|Wl into a single [64][64] weight so the 2nd aggregation is one 64-ch pass
__global__ void wcat_kernel(const float* __restrict__ Wm, const float* __restrict__ Wl,
                            float* __restrict__ Wcat) {
    int t = blockIdx.x * blockDim.x + threadIdx.x;
    if (t >= 64 * 64) return;
    int k = t >> 6, c = t & 63;
    Wcat[t] = (c < 32) ? Wm[k * 32 + c] : Wl[k * 32 + (c - 32)];
}

// ---------------- launch ----------------

extern "C" void kernel_launch(void* const* d_in, const int* in_sizes, int n_in,
                              void* d_out, int out_size, void* d_ws, size_t ws_size,
                              hipStream_t stream) {
    const float* x  = (const float*)d_in[0];
    const int*   ei = (const int*)d_in[1];   // int32! (JAX default int, per harness contract)
    const float* W0 = (const float*)d_in[2];
    const float* b0 = (const float*)d_in[3];
    const float* Wm = (const float*)d_in[4];
    const float* bm = (const float*)d_in[5];
    const float* Wl = (const float*)d_in[6];
    const float* bl = (const float*)d_in[7];
    float* out = (float*)d_out;

    int N = in_sizes[0] / 128;
    int E = in_sizes[1] / 2;
    const int* src = ei;
    const int* dst = ei + E;

    char* p = (char*)d_ws;
    auto carve = [&](size_t bytes) -> void* {
        void* q = (void*)p;
        p += (bytes + 255) & ~(size_t)255;
        return q;
    };
    int*   count   = (int*)carve((size_t)N * 4);          // also reused as fill
    int*   row_ptr = (int*)carve(((size_t)N + 1) * 4);
    int*   col     = (int*)carve((size_t)E * 4);
    float* dinv    = (float*)carve((size_t)N * 4);
    float* h0      = (float*)carve((size_t)N * 64 * 4);   // x@W0, later reused for h@Wcat
    float* h       = (float*)carve((size_t)N * 64 * 4);   // relu'd hidden
    float* Wcat    = (float*)carve(64 * 64 * 4);

    hipMemsetAsync(count, 0, (size_t)N * 4, stream);
    hist_kernel<<<2048, 256, 0, stream>>>(dst, E, count);
    dinv_kernel<<<(N + 255) / 256, 256, 0, stream>>>(count, dinv, N);
    scan_kernel<<<1, 1024, 0, stream>>>(count, row_ptr, N);
    hipMemsetAsync(count, 0, (size_t)N * 4, stream);
    scatter_kernel<<<2048, 256, 0, stream>>>(src, dst, E, row_ptr, count, col);

    // layer 0: h0 = x @ W0 ; h = relu(agg(h0) + b0)
    gemm_kernel<128><<<(N + 63) / 64, 256, 0, stream>>>(x, W0, h0, N);
    agg_relu_kernel<<<(N * 64 + 255) / 256, 256, 0, stream>>>(h0, row_ptr, col, dinv, b0, h, N);

    // layers mean/logstd fused: hml = h @ [Wm|Wl] ; out = agg(hml) + [bm|bl]
    wcat_kernel<<<16, 256, 0, stream>>>(Wm, Wl, Wcat);
    gemm_kernel<64><<<(N + 63) / 64, 256, 0, stream>>>(h, Wcat, h0, N);
    agg_out_kernel<<<(N * 64 + 255) / 256, 256, 0, stream>>>(h0, row_ptr, col, dinv, bm, bl, out, N);
}

// Round 3
// 700.656 us; speedup vs baseline: 1.0470x; 1.0470x over previous
//
#include <hip/hip_runtime.h>

// ---------------- preprocessing: degree histogram, scan, CSR scatter ----------------

__global__ void hist_kernel(const int* __restrict__ dst, int E, int* __restrict__ count) {
    int stride = gridDim.x * blockDim.x;
    int t = blockIdx.x * blockDim.x + threadIdx.x;
    int E4 = E >> 2;
    for (int e = t; e < E4; e += stride) {
        int4 d = ((const int4*)dst)[e];
        atomicAdd(&count[d.x], 1);
        atomicAdd(&count[d.y], 1);
        atomicAdd(&count[d.z], 1);
        atomicAdd(&count[d.w], 1);
    }
    for (int e = (E4 << 2) + t; e < E; e += stride) atomicAdd(&count[dst[e]], 1);
}

__global__ void dinv_kernel(const int* __restrict__ count, float* __restrict__ dinv, int N) {
    int i = blockIdx.x * blockDim.x + threadIdx.x;
    if (i < N) dinv[i] = 1.0f / sqrtf((float)count[i] + 1.0f);
}

// single-block exclusive scan over N counts -> row_ptr[0..N]
__global__ void scan_kernel(const int* __restrict__ count, int* __restrict__ row_ptr, int N) {
    __shared__ int buf[2][1024];
    int t = threadIdx.x;
    int chunk = (N + 1023) >> 10;
    int lo = min(t * chunk, N), hi = min(lo + chunk, N);
    int s = 0;
    for (int i = lo; i < hi; ++i) s += count[i];
    buf[0][t] = s;
    __syncthreads();
    int pi = 0;
    for (int off = 1; off < 1024; off <<= 1) {
        int v = buf[pi][t];
        if (t >= off) v += buf[pi][t - off];
        buf[pi ^ 1][t] = v;
        pi ^= 1;
        __syncthreads();
    }
    int run = (t == 0) ? 0 : buf[pi][t - 1];
    for (int i = lo; i < hi; ++i) { row_ptr[i] = run; run += count[i]; }
    if (lo < N && hi == N) row_ptr[N] = run;
}

__global__ void scatter_kernel(const int* __restrict__ src, const int* __restrict__ dst, int E,
                               const int* __restrict__ row_ptr, int* __restrict__ fill,
                               int* __restrict__ col) {
    int stride = gridDim.x * blockDim.x;
    int t = blockIdx.x * blockDim.x + threadIdx.x;
    int E4 = E >> 2;
    for (int e = t; e < E4; e += stride) {
        int4 s = ((const int4*)src)[e];
        int4 d = ((const int4*)dst)[e];
        col[row_ptr[d.x] + atomicAdd(&fill[d.x], 1)] = s.x;
        col[row_ptr[d.y] + atomicAdd(&fill[d.y], 1)] = s.y;
        col[row_ptr[d.z] + atomicAdd(&fill[d.z], 1)] = s.z;
        col[row_ptr[d.w] + atomicAdd(&fill[d.w], 1)] = s.w;
    }
    for (int e = (E4 << 2) + t; e < E; e += stride) {
        int d = dst[e];
        col[row_ptr[d] + atomicAdd(&fill[d], 1)] = src[e];
    }
}

// ---------------- fp32 GEMM: Out[M][64] = A[M][K] @ W[K][64] ----------------
template <int K>
__global__ __launch_bounds__(256, 2) void gemm_kernel(const float* __restrict__ A,
                                                      const float* __restrict__ W,
                                                      float* __restrict__ Out, int M) {
    __shared__ float Ws[K][64];
    __shared__ float As[64][68];
    int t = threadIdx.x;
    for (int i = t * 4; i < K * 64; i += 1024)
        *(float4*)&Ws[i >> 6][i & 63] = *(const float4*)(W + i);

    int row0 = blockIdx.x * 64;
    int rt = (t >> 4) * 4;
    int ct = (t & 15) * 4;
    float acc[4][4];
#pragma unroll
    for (int m = 0; m < 4; m++) { acc[m][0] = 0.f; acc[m][1] = 0.f; acc[m][2] = 0.f; acc[m][3] = 0.f; }

    for (int k0 = 0; k0 < K; k0 += 64) {
        __syncthreads();
        for (int i = t * 4; i < 64 * 64; i += 1024) {
            int r = i >> 6, c = i & 63;
            int gr = row0 + r;
            float4 v = make_float4(0.f, 0.f, 0.f, 0.f);
            if (gr < M) v = *(const float4*)(A + (size_t)gr * K + k0 + c);
            *(float4*)&As[r][c] = v;
        }
        __syncthreads();
#pragma unroll
        for (int kk = 0; kk < 64; ++kk) {
            float a0 = As[rt + 0][kk], a1 = As[rt + 1][kk];
            float a2 = As[rt + 2][kk], a3 = As[rt + 3][kk];
            float4 w = *(float4*)&Ws[k0 + kk][ct];
            acc[0][0] += a0 * w.x; acc[0][1] += a0 * w.y; acc[0][2] += a0 * w.z; acc[0][3] += a0 * w.w;
            acc[1][0] += a1 * w.x; acc[1][1] += a1 * w.y; acc[1][2] += a1 * w.z; acc[1][3] += a1 * w.w;
            acc[2][0] += a2 * w.x; acc[2][1] += a2 * w.y; acc[2][2] += a2 * w.z; acc[2][3] += a2 * w.w;
            acc[3][0] += a3 * w.x; acc[3][1] += a3 * w.y; acc[3][2] += a3 * w.z; acc[3][3] += a3 * w.w;
        }
    }
#pragma unroll
    for (int m = 0; m < 4; m++) {
        int gr = row0 + rt + m;
        if (gr < M)
            *(float4*)(Out + (size_t)gr * 64 + ct) =
                make_float4(acc[m][0], acc[m][1], acc[m][2], acc[m][3]);
    }
}

// same GEMM but K=64 with W = concat(Wm[64][32] | Wl[64][32]) staged directly in LDS
__global__ __launch_bounds__(256, 2) void gemm_cat_kernel(const float* __restrict__ A,
                                                          const float* __restrict__ Wm,
                                                          const float* __restrict__ Wl,
                                                          float* __restrict__ Out, int M) {
    __shared__ float Ws[64][64];
    __shared__ float As[64][68];
    int t = threadIdx.x;
    for (int i = t * 4; i < 64 * 32; i += 1024) {
        int k = i >> 5, c = i & 31;
        *(float4*)&Ws[k][c]      = *(const float4*)(Wm + i);
        *(float4*)&Ws[k][32 + c] = *(const float4*)(Wl + i);
    }

    int row0 = blockIdx.x * 64;
    int rt = (t >> 4) * 4;
    int ct = (t & 15) * 4;
    float acc[4][4];
#pragma unroll
    for (int m = 0; m < 4; m++) { acc[m][0] = 0.f; acc[m][1] = 0.f; acc[m][2] = 0.f; acc[m][3] = 0.f; }

    __syncthreads();
    for (int i = t * 4; i < 64 * 64; i += 1024) {
        int r = i >> 6, c = i & 63;
        int gr = row0 + r;
        float4 v = make_float4(0.f, 0.f, 0.f, 0.f);
        if (gr < M) v = *(const float4*)(A + (size_t)gr * 64 + c);
        *(float4*)&As[r][c] = v;
    }
    __syncthreads();
#pragma unroll
    for (int kk = 0; kk < 64; ++kk) {
        float a0 = As[rt + 0][kk], a1 = As[rt + 1][kk];
        float a2 = As[rt + 2][kk], a3 = As[rt + 3][kk];
        float4 w = *(float4*)&Ws[kk][ct];
        acc[0][0] += a0 * w.x; acc[0][1] += a0 * w.y; acc[0][2] += a0 * w.z; acc[0][3] += a0 * w.w;
        acc[1][0] += a1 * w.x; acc[1][1] += a1 * w.y; acc[1][2] += a1 * w.z; acc[1][3] += a1 * w.w;
        acc[2][0] += a2 * w.x; acc[2][1] += a2 * w.y; acc[2][2] += a2 * w.z; acc[2][3] += a2 * w.w;
        acc[3][0] += a3 * w.x; acc[3][1] += a3 * w.y; acc[3][2] += a3 * w.z; acc[3][3] += a3 * w.w;
    }
#pragma unroll
    for (int m = 0; m < 4; m++) {
        int gr = row0 + rt + m;
        if (gr < M)
            *(float4*)(Out + (size_t)gr * 64 + ct) =
                make_float4(acc[m][0], acc[m][1], acc[m][2], acc[m][3]);
    }
}

// ---------------- edge aggregation: one wave per node, 4 edges in flight ----------------
// wave = 4 groups x 16 lanes; group g handles edges beg+g (mod 4), lane l covers channels 4l..4l+3.
// result(lane) = di * ( sum_edges dinv[s]*Hin[s][c] + di*Hin[i][c] )   (c = 4*(lane&15))

__device__ __forceinline__ float4 agg_node(const float* __restrict__ Hin,
                                           const int* __restrict__ row_ptr,
                                           const int* __restrict__ col,
                                           const float* __restrict__ dinv,
                                           int i, int lane) {
    int g = lane >> 4;
    int l = lane & 15;
    float di = dinv[i];
    int beg = row_ptr[i], end = row_ptr[i + 1];
    float4 acc = make_float4(0.f, 0.f, 0.f, 0.f);
    if (g == 0) {
        float4 v = *(const float4*)(Hin + (size_t)i * 64 + l * 4);
        acc.x = di * v.x; acc.y = di * v.y; acc.z = di * v.z; acc.w = di * v.w;
    }
    for (int e = beg; e < end; e += 8) {
        int i0 = e + g, i1 = i0 + 4;
        int s0 = (i0 < end) ? col[i0] : 0;
        int s1 = (i1 < end) ? col[i1] : 0;
        float w0 = (i0 < end) ? dinv[s0] : 0.f;
        float w1 = (i1 < end) ? dinv[s1] : 0.f;
        float4 v0 = *(const float4*)(Hin + (size_t)s0 * 64 + l * 4);
        float4 v1 = *(const float4*)(Hin + (size_t)s1 * 64 + l * 4);
        acc.x = fmaf(w0, v0.x, acc.x); acc.y = fmaf(w0, v0.y, acc.y);
        acc.z = fmaf(w0, v0.z, acc.z); acc.w = fmaf(w0, v0.w, acc.w);
        acc.x = fmaf(w1, v1.x, acc.x); acc.y = fmaf(w1, v1.y, acc.y);
        acc.z = fmaf(w1, v1.z, acc.z); acc.w = fmaf(w1, v1.w, acc.w);
    }
    // reduce across the 4 groups (lane bits 4 and 5)
    acc.x += __shfl_xor(acc.x, 16); acc.y += __shfl_xor(acc.y, 16);
    acc.z += __shfl_xor(acc.z, 16); acc.w += __shfl_xor(acc.w, 16);
    acc.x += __shfl_xor(acc.x, 32); acc.y += __shfl_xor(acc.y, 32);
    acc.z += __shfl_xor(acc.z, 32); acc.w += __shfl_xor(acc.w, 32);
    acc.x *= di; acc.y *= di; acc.z *= di; acc.w *= di;
    return acc;
}

__global__ void agg_relu_kernel(const float* __restrict__ Hin, const int* __restrict__ row_ptr,
                                const int* __restrict__ col, const float* __restrict__ dinv,
                                const float* __restrict__ bias, float* __restrict__ Hout, int N) {
    int wid = (blockIdx.x * blockDim.x + threadIdx.x) >> 6;
    if (wid >= N) return;
    int lane = threadIdx.x & 63;
    float4 r = agg_node(Hin, row_ptr, col, dinv, wid, lane);
    if (lane < 16) {
        float4 b = *(const float4*)(bias + lane * 4);
        r.x = fmaxf(r.x + b.x, 0.f); r.y = fmaxf(r.y + b.y, 0.f);
        r.z = fmaxf(r.z + b.z, 0.f); r.w = fmaxf(r.w + b.w, 0.f);
        *(float4*)(Hout + (size_t)wid * 64 + lane * 4) = r;
    }
}

__global__ void agg_out_kernel(const float* __restrict__ Hin, const int* __restrict__ row_ptr,
                               const int* __restrict__ col, const float* __restrict__ dinv,
                               const float* __restrict__ bm, const float* __restrict__ bl,
                               float* __restrict__ out, int N) {
    int wid = (blockIdx.x * blockDim.x + threadIdx.x) >> 6;
    if (wid >= N) return;
    int lane = threadIdx.x & 63;
    float4 r = agg_node(Hin, row_ptr, col, dinv, wid, lane);
    if (lane < 8) {  // mean: channels 0..31
        float4 b = *(const float4*)(bm + lane * 4);
        r.x += b.x; r.y += b.y; r.z += b.z; r.w += b.w;
        *(float4*)(out + (size_t)wid * 32 + lane * 4) = r;
    } else if (lane < 16) {  // logstd: channels 32..63
        int l = lane - 8;
        float4 b = *(const float4*)(bl + l * 4);
        r.x += b.x; r.y += b.y; r.z += b.z; r.w += b.w;
        *(float4*)(out + (size_t)(N + wid) * 32 + l * 4) = r;
    }
}

// ---------------- launch ----------------

extern "C" void kernel_launch(void* const* d_in, const int* in_sizes, int n_in,
                              void* d_out, int out_size, void* d_ws, size_t ws_size,
                              hipStream_t stream) {
    const float* x  = (const float*)d_in[0];
    const int*   ei = (const int*)d_in[1];   // int32 (JAX default int)
    const float* W0 = (const float*)d_in[2];
    const float* b0 = (const float*)d_in[3];
    const float* Wm = (const float*)d_in[4];
    const float* bm = (const float*)d_in[5];
    const float* Wl = (const float*)d_in[6];
    const float* bl = (const float*)d_in[7];
    float* out = (float*)d_out;

    int N = in_sizes[0] / 128;
    int E = in_sizes[1] / 2;
    const int* src = ei;
    const int* dst = ei + E;

    char* p = (char*)d_ws;
    auto carve = [&](size_t bytes) -> void* {
        void* q = (void*)p;
        p += (bytes + 255) & ~(size_t)255;
        return q;
    };
    int*   count   = (int*)carve((size_t)N * 4);          // reused as fill
    int*   row_ptr = (int*)carve(((size_t)N + 1) * 4);
    int*   col     = (int*)carve((size_t)E * 4);
    float* dinv    = (float*)carve((size_t)N * 4);
    float* h0      = (float*)carve((size_t)N * 64 * 4);   // x@W0, later h@[Wm|Wl]
    float* h       = (float*)carve((size_t)N * 64 * 4);   // relu'd hidden

    hipMemsetAsync(count, 0, (size_t)N * 4, stream);
    hist_kernel<<<2048, 256, 0, stream>>>(dst, E, count);
    dinv_kernel<<<(N + 255) / 256, 256, 0, stream>>>(count, dinv, N);
    scan_kernel<<<1, 1024, 0, stream>>>(count, row_ptr, N);
    hipMemsetAsync(count, 0, (size_t)N * 4, stream);
    scatter_kernel<<<2048, 256, 0, stream>>>(src, dst, E, row_ptr, count, col);

    int aggGrid = (N + 3) / 4;  // 4 waves (nodes) per 256-thread block

    // layer 0: h0 = x @ W0 ; h = relu(agg(h0) + b0)
    gemm_kernel<128><<<(N + 63) / 64, 256, 0, stream>>>(x, W0, h0, N);
    agg_relu_kernel<<<aggGrid, 256, 0, stream>>>(h0, row_ptr, col, dinv, b0, h, N);

    // mean/logstd fused: hml = h @ [Wm|Wl] ; out = agg(hml) + [bm|bl]
    gemm_cat_kernel<<<(N + 63) / 64, 256, 0, stream>>>(h, Wm, Wl, h0, N);
    agg_out_kernel<<<aggGrid, 256, 0, stream>>>(h0, row_ptr, col, dinv, bm, bl, out, N);
}

// Round 4
// 526.789 us; speedup vs baseline: 1.3925x; 1.3300x over previous
//
#include <hip/hip_runtime.h>

// ---------------- preprocessing: degree histogram, scan, CSR scatter ----------------

__global__ void hist_kernel(const int* __restrict__ dst, int E, int* __restrict__ count) {
    int stride = gridDim.x * blockDim.x;
    int t = blockIdx.x * blockDim.x + threadIdx.x;
    int E4 = E >> 2;
    for (int e = t; e < E4; e += stride) {
        int4 d = ((const int4*)dst)[e];
        atomicAdd(&count[d.x], 1);
        atomicAdd(&count[d.y], 1);
        atomicAdd(&count[d.z], 1);
        atomicAdd(&count[d.w], 1);
    }
    for (int e = (E4 << 2) + t; e < E; e += stride) atomicAdd(&count[dst[e]], 1);
}

__global__ void dinv_kernel(const int* __restrict__ count, float* __restrict__ dinv, int N) {
    int i = blockIdx.x * blockDim.x + threadIdx.x;
    if (i < N) dinv[i] = 1.0f / sqrtf((float)count[i] + 1.0f);
}

// single-block exclusive scan over N counts -> row_ptr[0..N]
__global__ void scan_kernel(const int* __restrict__ count, int* __restrict__ row_ptr, int N) {
    __shared__ int buf[2][1024];
    int t = threadIdx.x;
    int chunk = (N + 1023) >> 10;
    int lo = min(t * chunk, N), hi = min(lo + chunk, N);
    int s = 0;
    for (int i = lo; i < hi; ++i) s += count[i];
    buf[0][t] = s;
    __syncthreads();
    int pi = 0;
    for (int off = 1; off < 1024; off <<= 1) {
        int v = buf[pi][t];
        if (t >= off) v += buf[pi][t - off];
        buf[pi ^ 1][t] = v;
        pi ^= 1;
        __syncthreads();
    }
    int run = (t == 0) ? 0 : buf[pi][t - 1];
    for (int i = lo; i < hi; ++i) { row_ptr[i] = run; run += count[i]; }
    if (lo < N && hi == N) row_ptr[N] = run;
}

__global__ void scatter_kernel(const int* __restrict__ src, const int* __restrict__ dst, int E,
                               const int* __restrict__ row_ptr, int* __restrict__ fill,
                               int* __restrict__ col) {
    int stride = gridDim.x * blockDim.x;
    int t = blockIdx.x * blockDim.x + threadIdx.x;
    int E4 = E >> 2;
    for (int e = t; e < E4; e += stride) {
        int4 s = ((const int4*)src)[e];
        int4 d = ((const int4*)dst)[e];
        col[row_ptr[d.x] + atomicAdd(&fill[d.x], 1)] = s.x;
        col[row_ptr[d.y] + atomicAdd(&fill[d.y], 1)] = s.y;
        col[row_ptr[d.z] + atomicAdd(&fill[d.z], 1)] = s.z;
        col[row_ptr[d.w] + atomicAdd(&fill[d.w], 1)] = s.w;
    }
    for (int e = (E4 << 2) + t; e < E; e += stride) {
        int d = dst[e];
        col[row_ptr[d] + atomicAdd(&fill[d], 1)] = src[e];
    }
}

// ---------------- fp32 GEMM: Out[M][64] = A[M][128] @ W[128][64] (layer-1 transform) -----

__global__ __launch_bounds__(256, 2) void gemm_kernel(const float* __restrict__ A,
                                                      const float* __restrict__ W,
                                                      float* __restrict__ Out, int M) {
    const int K = 128;
    __shared__ float Ws[K][64];
    __shared__ float As[64][68];
    int t = threadIdx.x;
    for (int i = t * 4; i < K * 64; i += 1024)
        *(float4*)&Ws[i >> 6][i & 63] = *(const float4*)(W + i);

    int row0 = blockIdx.x * 64;
    int rt = (t >> 4) * 4;
    int ct = (t & 15) * 4;
    float acc[4][4];
#pragma unroll
    for (int m = 0; m < 4; m++) { acc[m][0] = 0.f; acc[m][1] = 0.f; acc[m][2] = 0.f; acc[m][3] = 0.f; }

    for (int k0 = 0; k0 < K; k0 += 64) {
        __syncthreads();
        for (int i = t * 4; i < 64 * 64; i += 1024) {
            int r = i >> 6, c = i & 63;
            int gr = row0 + r;
            float4 v = make_float4(0.f, 0.f, 0.f, 0.f);
            if (gr < M) v = *(const float4*)(A + (size_t)gr * K + k0 + c);
            *(float4*)&As[r][c] = v;
        }
        __syncthreads();
#pragma unroll
        for (int kk = 0; kk < 64; ++kk) {
            float a0 = As[rt + 0][kk], a1 = As[rt + 1][kk];
            float a2 = As[rt + 2][kk], a3 = As[rt + 3][kk];
            float4 w = *(float4*)&Ws[k0 + kk][ct];
            acc[0][0] += a0 * w.x; acc[0][1] += a0 * w.y; acc[0][2] += a0 * w.z; acc[0][3] += a0 * w.w;
            acc[1][0] += a1 * w.x; acc[1][1] += a1 * w.y; acc[1][2] += a1 * w.z; acc[1][3] += a1 * w.w;
            acc[2][0] += a2 * w.x; acc[2][1] += a2 * w.y; acc[2][2] += a2 * w.z; acc[2][3] += a2 * w.w;
            acc[3][0] += a3 * w.x; acc[3][1] += a3 * w.y; acc[3][2] += a3 * w.z; acc[3][3] += a3 * w.w;
        }
    }
#pragma unroll
    for (int m = 0; m < 4; m++) {
        int gr = row0 + rt + m;
        if (gr < M)
            *(float4*)(Out + (size_t)gr * 64 + ct) =
                make_float4(acc[m][0], acc[m][1], acc[m][2], acc[m][3]);
    }
}

// ---------------- edge aggregation core: one wave per node, 8 edges in flight ------------
// wave = 4 groups x 16 lanes; group g handles edges (beg+g) mod 4; lane l covers channels
// 4*(l&15)..+3.  After the xor-butterfly ALL 64 lanes hold the reduced float4 for their
// channel block:  acc = di * ( sum_e dinv[src_e]*Hin[src_e][c] + di*Hin[i][c] ).

__device__ __forceinline__ float4 agg_node(const float* __restrict__ Hin,
                                           const int* __restrict__ row_ptr,
                                           const int* __restrict__ col,
                                           const float* __restrict__ dinv,
                                           int i, int lane) {
    int g = lane >> 4;
    int l = lane & 15;
    float di = dinv[i];
    int beg = row_ptr[i], end = row_ptr[i + 1];
    float4 acc = make_float4(0.f, 0.f, 0.f, 0.f);
    if (g == 0) {
        float4 v = *(const float4*)(Hin + (size_t)i * 64 + l * 4);
        acc.x = di * v.x; acc.y = di * v.y; acc.z = di * v.z; acc.w = di * v.w;
    }
    for (int e = beg; e < end; e += 8) {
        int i0 = e + g, i1 = i0 + 4;
        int s0 = (i0 < end) ? col[i0] : 0;
        int s1 = (i1 < end) ? col[i1] : 0;
        float w0 = (i0 < end) ? dinv[s0] : 0.f;
        float w1 = (i1 < end) ? dinv[s1] : 0.f;
        float4 v0 = *(const float4*)(Hin + (size_t)s0 * 64 + l * 4);
        float4 v1 = *(const float4*)(Hin + (size_t)s1 * 64 + l * 4);
        acc.x = fmaf(w0, v0.x, acc.x); acc.y = fmaf(w0, v0.y, acc.y);
        acc.z = fmaf(w0, v0.z, acc.z); acc.w = fmaf(w0, v0.w, acc.w);
        acc.x = fmaf(w1, v1.x, acc.x); acc.y = fmaf(w1, v1.y, acc.y);
        acc.z = fmaf(w1, v1.z, acc.z); acc.w = fmaf(w1, v1.w, acc.w);
    }
    acc.x += __shfl_xor(acc.x, 16); acc.y += __shfl_xor(acc.y, 16);
    acc.z += __shfl_xor(acc.z, 16); acc.w += __shfl_xor(acc.w, 16);
    acc.x += __shfl_xor(acc.x, 32); acc.y += __shfl_xor(acc.y, 32);
    acc.z += __shfl_xor(acc.z, 32); acc.w += __shfl_xor(acc.w, 32);
    acc.x *= di; acc.y *= di; acc.z *= di; acc.w *= di;
    return acc;
}

// layer 1: h = relu(agg(h0) + b0)
__global__ void agg_relu_kernel(const float* __restrict__ Hin, const int* __restrict__ row_ptr,
                                const int* __restrict__ col, const float* __restrict__ dinv,
                                const float* __restrict__ bias, float* __restrict__ Hout, int N) {
    int wid = (blockIdx.x * blockDim.x + threadIdx.x) >> 6;
    if (wid >= N) return;
    int lane = threadIdx.x & 63;
    float4 r = agg_node(Hin, row_ptr, col, dinv, wid, lane);
    if (lane < 16) {
        float4 b = *(const float4*)(bias + lane * 4);
        r.x = fmaxf(r.x + b.x, 0.f); r.y = fmaxf(r.y + b.y, 0.f);
        r.z = fmaxf(r.z + b.z, 0.f); r.w = fmaxf(r.w + b.w, 0.f);
        *(float4*)(Hout + (size_t)wid * 64 + lane * 4) = r;
    }
}

// layer 2 FUSED: g = agg(h); out = [ g@Wm + bm | g@Wl + bl ]   (agg is linear, so
// agg(h@W) == agg(h)@W -- the 64x64 GEMM folds into the aggregation epilogue)
__global__ __launch_bounds__(256) void agg_out_fused_kernel(
        const float* __restrict__ Hin, const int* __restrict__ row_ptr,
        const int* __restrict__ col, const float* __restrict__ dinv,
        const float* __restrict__ Wm, const float* __restrict__ Wl,
        const float* __restrict__ bm, const float* __restrict__ bl,
        float* __restrict__ out, int N) {
    __shared__ float Ws[64][64];  // [k][j] : j<32 -> Wm[k][j], j>=32 -> Wl[k][j-32]
    int t = threadIdx.x;
    for (int i = t * 4; i < 64 * 32; i += 1024) {
        int k = i >> 5, c = i & 31;
        *(float4*)&Ws[k][c]      = *(const float4*)(Wm + i);
        *(float4*)&Ws[k][32 + c] = *(const float4*)(Wl + i);
    }
    __syncthreads();

    int lane = t & 63;
    float bj = (lane < 32) ? bm[lane] : bl[lane - 32];

    int gw = (blockIdx.x * blockDim.x + t) >> 6;       // global wave id
    int TW = (gridDim.x * blockDim.x) >> 6;            // total waves
    for (int i = gw; i < N; i += TW) {
        float4 r = agg_node(Hin, row_ptr, col, dinv, i, lane);
        float a[4] = {r.x, r.y, r.z, r.w};
        // out[j] = sum_k g[k] * Ws[k][j] + b[j]; g[k] lives in lane (k>>2), comp (k&3)
        float o = bj;
#pragma unroll
        for (int k = 0; k < 64; ++k) {
            float gk = __shfl(a[k & 3], k >> 2, 64);
            o = fmaf(gk, Ws[k][lane], o);
        }
        if (lane < 32) out[(size_t)i * 32 + lane] = o;
        else           out[(size_t)(N + i) * 32 + (lane - 32)] = o;
    }
}

// ---------------- launch ----------------

extern "C" void kernel_launch(void* const* d_in, const int* in_sizes, int n_in,
                              void* d_out, int out_size, void* d_ws, size_t ws_size,
                              hipStream_t stream) {
    const float* x  = (const float*)d_in[0];
    const int*   ei = (const int*)d_in[1];   // int32 (JAX default int)
    const float* W0 = (const float*)d_in[2];
    const float* b0 = (const float*)d_in[3];
    const float* Wm = (const float*)d_in[4];
    const float* bm = (const float*)d_in[5];
    const float* Wl = (const float*)d_in[6];
    const float* bl = (const float*)d_in[7];
    float* out = (float*)d_out;

    int N = in_sizes[0] / 128;
    int E = in_sizes[1] / 2;
    const int* src = ei;
    const int* dst = ei + E;

    char* p = (char*)d_ws;
    auto carve = [&](size_t bytes) -> void* {
        void* q = (void*)p;
        p += (bytes + 255) & ~(size_t)255;
        return q;
    };
    int*   count   = (int*)carve((size_t)N * 4);          // reused as fill
    int*   row_ptr = (int*)carve(((size_t)N + 1) * 4);
    int*   col     = (int*)carve((size_t)E * 4);
    float* dinv    = (float*)carve((size_t)N * 4);
    float* h0      = (float*)carve((size_t)N * 64 * 4);   // x@W0
    float* h       = (float*)carve((size_t)N * 64 * 4);   // relu'd hidden

    hipMemsetAsync(count, 0, (size_t)N * 4, stream);
    hist_kernel<<<2048, 256, 0, stream>>>(dst, E, count);
    dinv_kernel<<<(N + 255) / 256, 256, 0, stream>>>(count, dinv, N);
    scan_kernel<<<1, 1024, 0, stream>>>(count, row_ptr, N);
    hipMemsetAsync(count, 0, (size_t)N * 4, stream);
    scatter_kernel<<<2048, 256, 0, stream>>>(src, dst, E, row_ptr, count, col);

    // layer 0: h0 = x @ W0 ; h = relu(agg(h0) + b0)
    gemm_kernel<<<(N + 63) / 64, 256, 0, stream>>>(x, W0, h0, N);
    agg_relu_kernel<<<(N + 3) / 4, 256, 0, stream>>>(h0, row_ptr, col, dinv, b0, h, N);

    // layer 2 fused: out = [agg(h)@Wm + bm | agg(h)@Wl + bl]
    agg_out_fused_kernel<<<2048, 256, 0, stream>>>(h, row_ptr, col, dinv, Wm, Wl, bm, bl, out, N);
}

// Round 5
// 375.312 us; speedup vs baseline: 1.9545x; 1.4036x over previous
//
#include <hip/hip_runtime.h>

// ---------------- preprocessing: degree histogram, 3-phase scan (+dinv), CSR scatter ----

__global__ void hist_kernel(const int* __restrict__ dst, int E, int* __restrict__ count) {
    int stride = gridDim.x * blockDim.x;
    int t = blockIdx.x * blockDim.x + threadIdx.x;
    int E4 = E >> 2;
    for (int e = t; e < E4; e += stride) {
        int4 d = ((const int4*)dst)[e];
        atomicAdd(&count[d.x], 1);
        atomicAdd(&count[d.y], 1);
        atomicAdd(&count[d.z], 1);
        atomicAdd(&count[d.w], 1);
    }
    for (int e = (E4 << 2) + t; e < E; e += stride) atomicAdd(&count[dst[e]], 1);
}

// phase 1: per-block (1024 counts) partial sums
__global__ void scan_partial_kernel(const int* __restrict__ count, int* __restrict__ partials,
                                    int N) {
    __shared__ int red[4];
    int t = threadIdx.x;
    int idx = blockIdx.x * 1024 + t * 4;
    int s = 0;
    if (idx + 3 < N) {
        int4 c = *(const int4*)(count + idx);
        s = c.x + c.y + c.z + c.w;
    } else {
#pragma unroll
        for (int k = 0; k < 4; ++k)
            if (idx + k < N) s += count[idx + k];
    }
#pragma unroll
    for (int off = 1; off < 64; off <<= 1) s += __shfl_xor(s, off);
    if ((t & 63) == 0) red[t >> 6] = s;
    __syncthreads();
    if (t == 0) partials[blockIdx.x] = red[0] + red[1] + red[2] + red[3];
}

// phase 2: exclusive scan of the (<=128) partials; also writes row_ptr[N] = total
__global__ void scan_top_kernel(int* __restrict__ partials, int nb, int* __restrict__ row_ptr,
                                int N) {
    __shared__ int buf[2][128];
    int t = threadIdx.x;
    buf[0][t] = (t < nb) ? partials[t] : 0;
    __syncthreads();
    int pi = 0;
    for (int off = 1; off < 128; off <<= 1) {
        int v = buf[pi][t];
        if (t >= off) v += buf[pi][t - off];
        buf[pi ^ 1][t] = v;
        pi ^= 1;
        __syncthreads();
    }
    if (t < nb) partials[t] = (t == 0) ? 0 : buf[pi][t - 1];
    if (t == 0) row_ptr[N] = buf[pi][127];
}

// phase 3: in-block exclusive scan + block offset -> row_ptr; dinv fused
__global__ void scan_apply_kernel(const int* __restrict__ count, const int* __restrict__ partials,
                                  int* __restrict__ row_ptr, float* __restrict__ dinv, int N) {
    __shared__ int wsum[4];
    int t = threadIdx.x;
    int idx = blockIdx.x * 1024 + t * 4;
    int4 c = make_int4(0, 0, 0, 0);
    if (idx + 3 < N) {
        c = *(const int4*)(count + idx);
    } else {
        if (idx + 0 < N) c.x = count[idx + 0];
        if (idx + 1 < N) c.y = count[idx + 1];
        if (idx + 2 < N) c.z = count[idx + 2];
    }
    int s = c.x + c.y + c.z + c.w;
    int incl = s;
#pragma unroll
    for (int off = 1; off < 64; off <<= 1) {
        int v = __shfl_up(incl, off);
        if ((t & 63) >= off) incl += v;
    }
    int wexcl = incl - s;
    int w = t >> 6;
    if ((t & 63) == 63) wsum[w] = incl;
    __syncthreads();
    int base = partials[blockIdx.x] + wexcl;
    for (int k = 0; k < w; ++k) base += wsum[k];
    if (idx + 0 < N) { row_ptr[idx + 0] = base;                   dinv[idx + 0] = rsqrtf((float)c.x + 1.f); }
    if (idx + 1 < N) { row_ptr[idx + 1] = base + c.x;             dinv[idx + 1] = rsqrtf((float)c.y + 1.f); }
    if (idx + 2 < N) { row_ptr[idx + 2] = base + c.x + c.y;       dinv[idx + 2] = rsqrtf((float)c.z + 1.f); }
    if (idx + 3 < N) { row_ptr[idx + 3] = base + c.x + c.y + c.z; dinv[idx + 3] = rsqrtf((float)c.w + 1.f); }
}

__global__ void scatter_kernel(const int* __restrict__ src, const int* __restrict__ dst, int E,
                               const int* __restrict__ row_ptr, int* __restrict__ fill,
                               int* __restrict__ col) {
    int stride = gridDim.x * blockDim.x;
    int t = blockIdx.x * blockDim.x + threadIdx.x;
    int E4 = E >> 2;
    for (int e = t; e < E4; e += stride) {
        int4 s = ((const int4*)src)[e];
        int4 d = ((const int4*)dst)[e];
        col[row_ptr[d.x] + atomicAdd(&fill[d.x], 1)] = s.x;
        col[row_ptr[d.y] + atomicAdd(&fill[d.y], 1)] = s.y;
        col[row_ptr[d.z] + atomicAdd(&fill[d.z], 1)] = s.z;
        col[row_ptr[d.w] + atomicAdd(&fill[d.w], 1)] = s.w;
    }
    for (int e = (E4 << 2) + t; e < E; e += stride) {
        int d = dst[e];
        col[row_ptr[d] + atomicAdd(&fill[d], 1)] = src[e];
    }
}

// ---------------- fp32 GEMM: Out[M][64] = A[M][128] @ W[128][64] (layer-1 transform) -----

__global__ __launch_bounds__(256, 2) void gemm_kernel(const float* __restrict__ A,
                                                      const float* __restrict__ W,
                                                      float* __restrict__ Out, int M) {
    const int K = 128;
    __shared__ float Ws[K][64];
    __shared__ float As[64][68];
    int t = threadIdx.x;
    for (int i = t * 4; i < K * 64; i += 1024)
        *(float4*)&Ws[i >> 6][i & 63] = *(const float4*)(W + i);

    int row0 = blockIdx.x * 64;
    int rt = (t >> 4) * 4;
    int ct = (t & 15) * 4;
    float acc[4][4];
#pragma unroll
    for (int m = 0; m < 4; m++) { acc[m][0] = 0.f; acc[m][1] = 0.f; acc[m][2] = 0.f; acc[m][3] = 0.f; }

    for (int k0 = 0; k0 < K; k0 += 64) {
        __syncthreads();
        for (int i = t * 4; i < 64 * 64; i += 1024) {
            int r = i >> 6, c = i & 63;
            int gr = row0 + r;
            float4 v = make_float4(0.f, 0.f, 0.f, 0.f);
            if (gr < M) v = *(const float4*)(A + (size_t)gr * K + k0 + c);
            *(float4*)&As[r][c] = v;
        }
        __syncthreads();
#pragma unroll
        for (int kk = 0; kk < 64; ++kk) {
            float a0 = As[rt + 0][kk], a1 = As[rt + 1][kk];
            float a2 = As[rt + 2][kk], a3 = As[rt + 3][kk];
            float4 w = *(float4*)&Ws[k0 + kk][ct];
            acc[0][0] += a0 * w.x; acc[0][1] += a0 * w.y; acc[0][2] += a0 * w.z; acc[0][3] += a0 * w.w;
            acc[1][0] += a1 * w.x; acc[1][1] += a1 * w.y; acc[1][2] += a1 * w.z; acc[1][3] += a1 * w.w;
            acc[2][0] += a2 * w.x; acc[2][1] += a2 * w.y; acc[2][2] += a2 * w.z; acc[2][3] += a2 * w.w;
            acc[3][0] += a3 * w.x; acc[3][1] += a3 * w.y; acc[3][2] += a3 * w.z; acc[3][3] += a3 * w.w;
        }
    }
#pragma unroll
    for (int m = 0; m < 4; m++) {
        int gr = row0 + rt + m;
        if (gr < M)
            *(float4*)(Out + (size_t)gr * 64 + ct) =
                make_float4(acc[m][0], acc[m][1], acc[m][2], acc[m][3]);
    }
}

// ---------------- edge aggregation core: one wave per node, 8 edges in flight ------------

__device__ __forceinline__ float4 agg_node(const float* __restrict__ Hin,
                                           const int* __restrict__ row_ptr,
                                           const int* __restrict__ col,
                                           const float* __restrict__ dinv,
                                           int i, int lane) {
    int g = lane >> 4;
    int l = lane & 15;
    float di = dinv[i];
    int beg = row_ptr[i], end = row_ptr[i + 1];
    float4 acc = make_float4(0.f, 0.f, 0.f, 0.f);
    if (g == 0) {
        float4 v = *(const float4*)(Hin + (size_t)i * 64 + l * 4);
        acc.x = di * v.x; acc.y = di * v.y; acc.z = di * v.z; acc.w = di * v.w;
    }
    for (int e = beg; e < end; e += 8) {
        int i0 = e + g, i1 = i0 + 4;
        int s0 = (i0 < end) ? col[i0] : 0;
        int s1 = (i1 < end) ? col[i1] : 0;
        float w0 = (i0 < end) ? dinv[s0] : 0.f;
        float w1 = (i1 < end) ? dinv[s1] : 0.f;
        float4 v0 = *(const float4*)(Hin + (size_t)s0 * 64 + l * 4);
        float4 v1 = *(const float4*)(Hin + (size_t)s1 * 64 + l * 4);
        acc.x = fmaf(w0, v0.x, acc.x); acc.y = fmaf(w0, v0.y, acc.y);
        acc.z = fmaf(w0, v0.z, acc.z); acc.w = fmaf(w0, v0.w, acc.w);
        acc.x = fmaf(w1, v1.x, acc.x); acc.y = fmaf(w1, v1.y, acc.y);
        acc.z = fmaf(w1, v1.z, acc.z); acc.w = fmaf(w1, v1.w, acc.w);
    }
    acc.x += __shfl_xor(acc.x, 16); acc.y += __shfl_xor(acc.y, 16);
    acc.z += __shfl_xor(acc.z, 16); acc.w += __shfl_xor(acc.w, 16);
    acc.x += __shfl_xor(acc.x, 32); acc.y += __shfl_xor(acc.y, 32);
    acc.z += __shfl_xor(acc.z, 32); acc.w += __shfl_xor(acc.w, 32);
    acc.x *= di; acc.y *= di; acc.z *= di; acc.w *= di;
    return acc;
}

// layer 1: h = relu(agg(h0) + b0)
__global__ void agg_relu_kernel(const float* __restrict__ Hin, const int* __restrict__ row_ptr,
                                const int* __restrict__ col, const float* __restrict__ dinv,
                                const float* __restrict__ bias, float* __restrict__ Hout, int N) {
    int wid = (blockIdx.x * blockDim.x + threadIdx.x) >> 6;
    if (wid >= N) return;
    int lane = threadIdx.x & 63;
    float4 r = agg_node(Hin, row_ptr, col, dinv, wid, lane);
    if (lane < 16) {
        float4 b = *(const float4*)(bias + lane * 4);
        r.x = fmaxf(r.x + b.x, 0.f); r.y = fmaxf(r.y + b.y, 0.f);
        r.z = fmaxf(r.z + b.z, 0.f); r.w = fmaxf(r.w + b.w, 0.f);
        *(float4*)(Hout + (size_t)wid * 64 + lane * 4) = r;
    }
}

// layer 2 FUSED: g = agg(h); out = [ g@Wm + bm | g@Wl + bl ]  (agg(h@W) == agg(h)@W)
__global__ __launch_bounds__(256) void agg_out_fused_kernel(
        const float* __restrict__ Hin, const int* __restrict__ row_ptr,
        const int* __restrict__ col, const float* __restrict__ dinv,
        const float* __restrict__ Wm, const float* __restrict__ Wl,
        const float* __restrict__ bm, const float* __restrict__ bl,
        float* __restrict__ out, int N) {
    __shared__ float Ws[64][64];
    int t = threadIdx.x;
    for (int i = t * 4; i < 64 * 32; i += 1024) {
        int k = i >> 5, c = i & 31;
        *(float4*)&Ws[k][c]      = *(const float4*)(Wm + i);
        *(float4*)&Ws[k][32 + c] = *(const float4*)(Wl + i);
    }
    __syncthreads();

    int lane = t & 63;
    float bj = (lane < 32) ? bm[lane] : bl[lane - 32];

    int gw = (blockIdx.x * blockDim.x + t) >> 6;
    int TW = (gridDim.x * blockDim.x) >> 6;
    for (int i = gw; i < N; i += TW) {
        float4 r = agg_node(Hin, row_ptr, col, dinv, i, lane);
        float a[4] = {r.x, r.y, r.z, r.w};
        float o = bj;
#pragma unroll
        for (int k = 0; k < 64; ++k) {
            float gk = __shfl(a[k & 3], k >> 2, 64);
            o = fmaf(gk, Ws[k][lane], o);
        }
        if (lane < 32) out[(size_t)i * 32 + lane] = o;
        else           out[(size_t)(N + i) * 32 + (lane - 32)] = o;
    }
}

// ---------------- launch ----------------

extern "C" void kernel_launch(void* const* d_in, const int* in_sizes, int n_in,
                              void* d_out, int out_size, void* d_ws, size_t ws_size,
                              hipStream_t stream) {
    const float* x  = (const float*)d_in[0];
    const int*   ei = (const int*)d_in[1];   // int32 (JAX default int)
    const float* W0 = (const float*)d_in[2];
    const float* b0 = (const float*)d_in[3];
    const float* Wm = (const float*)d_in[4];
    const float* bm = (const float*)d_in[5];
    const float* Wl = (const float*)d_in[6];
    const float* bl = (const float*)d_in[7];
    float* out = (float*)d_out;

    int N = in_sizes[0] / 128;
    int E = in_sizes[1] / 2;
    const int* src = ei;
    const int* dst = ei + E;

    char* p = (char*)d_ws;
    auto carve = [&](size_t bytes) -> void* {
        void* q = (void*)p;
        p += (bytes + 255) & ~(size_t)255;
        return q;
    };
    int*   count    = (int*)carve((size_t)N * 4);          // reused as fill
    int*   row_ptr  = (int*)carve(((size_t)N + 1) * 4);
    int*   col      = (int*)carve((size_t)E * 4);
    float* dinv     = (float*)carve((size_t)N * 4);
    int*   partials = (int*)carve(128 * 4);
    float* h0       = (float*)carve((size_t)N * 64 * 4);   // x@W0
    float* h        = (float*)carve((size_t)N * 64 * 4);   // relu'd hidden

    int nb = (N + 1023) / 1024;  // scan blocks (<=128 for N<=131072)

    hipMemsetAsync(count, 0, (size_t)N * 4, stream);
    hist_kernel<<<2048, 256, 0, stream>>>(dst, E, count);
    scan_partial_kernel<<<nb, 256, 0, stream>>>(count, partials, N);
    scan_top_kernel<<<1, 128, 0, stream>>>(partials, nb, row_ptr, N);
    scan_apply_kernel<<<nb, 256, 0, stream>>>(count, partials, row_ptr, dinv, N);
    hipMemsetAsync(count, 0, (size_t)N * 4, stream);
    scatter_kernel<<<2048, 256, 0, stream>>>(src, dst, E, row_ptr, count, col);

    // layer 0: h0 = x @ W0 ; h = relu(agg(h0) + b0)
    gemm_kernel<<<(N + 63) / 64, 256, 0, stream>>>(x, W0, h0, N);
    agg_relu_kernel<<<(N + 3) / 4, 256, 0, stream>>>(h0, row_ptr, col, dinv, b0, h, N);

    // layer 2 fused: out = [agg(h)@Wm + bm | agg(h)@Wl + bl]
    agg_out_fused_kernel<<<2048, 256, 0, stream>>>(h, row_ptr, col, dinv, Wm, Wl, bm, bl, out, N);
}

// Round 6
// 366.603 us; speedup vs baseline: 2.0010x; 1.0238x over previous
//
#include <hip/hip_runtime.h>
#include <hip/hip_fp16.h>

// ---------------- preprocessing: degree histogram, 3-phase scan (+dinv), CSR scatter ----

__global__ void hist_kernel(const int* __restrict__ dst, int E, int* __restrict__ count) {
    int stride = gridDim.x * blockDim.x;
    int t = blockIdx.x * blockDim.x + threadIdx.x;
    int E4 = E >> 2;
    for (int e = t; e < E4; e += stride) {
        int4 d = ((const int4*)dst)[e];
        atomicAdd(&count[d.x], 1);
        atomicAdd(&count[d.y], 1);
        atomicAdd(&count[d.z], 1);
        atomicAdd(&count[d.w], 1);
    }
    for (int e = (E4 << 2) + t; e < E; e += stride) atomicAdd(&count[dst[e]], 1);
}

// phase 1: per-block (1024 counts) partial sums
__global__ void scan_partial_kernel(const int* __restrict__ count, int* __restrict__ partials,
                                    int N) {
    __shared__ int red[4];
    int t = threadIdx.x;
    int idx = blockIdx.x * 1024 + t * 4;
    int s = 0;
    if (idx + 3 < N) {
        int4 c = *(const int4*)(count + idx);
        s = c.x + c.y + c.z + c.w;
    } else {
#pragma unroll
        for (int k = 0; k < 4; ++k)
            if (idx + k < N) s += count[idx + k];
    }
#pragma unroll
    for (int off = 1; off < 64; off <<= 1) s += __shfl_xor(s, off);
    if ((t & 63) == 0) red[t >> 6] = s;
    __syncthreads();
    if (t == 0) partials[blockIdx.x] = red[0] + red[1] + red[2] + red[3];
}

// phase 2: exclusive scan of the (<=128) partials; also writes row_ptr[N] = total
__global__ void scan_top_kernel(int* __restrict__ partials, int nb, int* __restrict__ row_ptr,
                                int N) {
    __shared__ int buf[2][128];
    int t = threadIdx.x;
    buf[0][t] = (t < nb) ? partials[t] : 0;
    __syncthreads();
    int pi = 0;
    for (int off = 1; off < 128; off <<= 1) {
        int v = buf[pi][t];
        if (t >= off) v += buf[pi][t - off];
        buf[pi ^ 1][t] = v;
        pi ^= 1;
        __syncthreads();
    }
    if (t < nb) partials[t] = (t == 0) ? 0 : buf[pi][t - 1];
    if (t == 0) row_ptr[N] = buf[pi][127];
}

// phase 3: in-block exclusive scan + block offset -> row_ptr; dinv fused
__global__ void scan_apply_kernel(const int* __restrict__ count, const int* __restrict__ partials,
                                  int* __restrict__ row_ptr, float* __restrict__ dinv, int N) {
    __shared__ int wsum[4];
    int t = threadIdx.x;
    int idx = blockIdx.x * 1024 + t * 4;
    int4 c = make_int4(0, 0, 0, 0);
    if (idx + 3 < N) {
        c = *(const int4*)(count + idx);
    } else {
        if (idx + 0 < N) c.x = count[idx + 0];
        if (idx + 1 < N) c.y = count[idx + 1];
        if (idx + 2 < N) c.z = count[idx + 2];
    }
    int s = c.x + c.y + c.z + c.w;
    int incl = s;
#pragma unroll
    for (int off = 1; off < 64; off <<= 1) {
        int v = __shfl_up(incl, off);
        if ((t & 63) >= off) incl += v;
    }
    int wexcl = incl - s;
    int w = t >> 6;
    if ((t & 63) == 63) wsum[w] = incl;
    __syncthreads();
    int base = partials[blockIdx.x] + wexcl;
    for (int k = 0; k < w; ++k) base += wsum[k];
    if (idx + 0 < N) { row_ptr[idx + 0] = base;                   dinv[idx + 0] = rsqrtf((float)c.x + 1.f); }
    if (idx + 1 < N) { row_ptr[idx + 1] = base + c.x;             dinv[idx + 1] = rsqrtf((float)c.y + 1.f); }
    if (idx + 2 < N) { row_ptr[idx + 2] = base + c.x + c.y;       dinv[idx + 2] = rsqrtf((float)c.z + 1.f); }
    if (idx + 3 < N) { row_ptr[idx + 3] = base + c.x + c.y + c.z; dinv[idx + 3] = rsqrtf((float)c.w + 1.f); }
}

__global__ void scatter_kernel(const int* __restrict__ src, const int* __restrict__ dst, int E,
                               const int* __restrict__ row_ptr, int* __restrict__ fill,
                               int* __restrict__ col) {
    int stride = gridDim.x * blockDim.x;
    int t = blockIdx.x * blockDim.x + threadIdx.x;
    int E4 = E >> 2;
    for (int e = t; e < E4; e += stride) {
        int4 s = ((const int4*)src)[e];
        int4 d = ((const int4*)dst)[e];
        col[row_ptr[d.x] + atomicAdd(&fill[d.x], 1)] = s.x;
        col[row_ptr[d.y] + atomicAdd(&fill[d.y], 1)] = s.y;
        col[row_ptr[d.z] + atomicAdd(&fill[d.z], 1)] = s.z;
        col[row_ptr[d.w] + atomicAdd(&fill[d.w], 1)] = s.w;
    }
    for (int e = (E4 << 2) + t; e < E; e += stride) {
        int d = dst[e];
        col[row_ptr[d] + atomicAdd(&fill[d], 1)] = src[e];
    }
}

// ------------- fp32 GEMM, fp16 output: Out[M][64] = A[M][128] @ W[128][64] --------------

__global__ __launch_bounds__(256, 2) void gemm_kernel(const float* __restrict__ A,
                                                      const float* __restrict__ W,
                                                      __half* __restrict__ Out, int M) {
    const int K = 128;
    __shared__ float Ws[K][64];
    __shared__ float As[64][68];
    int t = threadIdx.x;
    for (int i = t * 4; i < K * 64; i += 1024)
        *(float4*)&Ws[i >> 6][i & 63] = *(const float4*)(W + i);

    int row0 = blockIdx.x * 64;
    int rt = (t >> 4) * 4;
    int ct = (t & 15) * 4;
    float acc[4][4];
#pragma unroll
    for (int m = 0; m < 4; m++) { acc[m][0] = 0.f; acc[m][1] = 0.f; acc[m][2] = 0.f; acc[m][3] = 0.f; }

    for (int k0 = 0; k0 < K; k0 += 64) {
        __syncthreads();
        for (int i = t * 4; i < 64 * 64; i += 1024) {
            int r = i >> 6, c = i & 63;
            int gr = row0 + r;
            float4 v = make_float4(0.f, 0.f, 0.f, 0.f);
            if (gr < M) v = *(const float4*)(A + (size_t)gr * K + k0 + c);
            *(float4*)&As[r][c] = v;
        }
        __syncthreads();
#pragma unroll
        for (int kk = 0; kk < 64; ++kk) {
            float a0 = As[rt + 0][kk], a1 = As[rt + 1][kk];
            float a2 = As[rt + 2][kk], a3 = As[rt + 3][kk];
            float4 w = *(float4*)&Ws[k0 + kk][ct];
            acc[0][0] += a0 * w.x; acc[0][1] += a0 * w.y; acc[0][2] += a0 * w.z; acc[0][3] += a0 * w.w;
            acc[1][0] += a1 * w.x; acc[1][1] += a1 * w.y; acc[1][2] += a1 * w.z; acc[1][3] += a1 * w.w;
            acc[2][0] += a2 * w.x; acc[2][1] += a2 * w.y; acc[2][2] += a2 * w.z; acc[2][3] += a2 * w.w;
            acc[3][0] += a3 * w.x; acc[3][1] += a3 * w.y; acc[3][2] += a3 * w.z; acc[3][3] += a3 * w.w;
        }
    }
#pragma unroll
    for (int m = 0; m < 4; m++) {
        int gr = row0 + rt + m;
        if (gr < M) {
            union { uint2 u; __half h[4]; } pk;
            pk.h[0] = __float2half(acc[m][0]);
            pk.h[1] = __float2half(acc[m][1]);
            pk.h[2] = __float2half(acc[m][2]);
            pk.h[3] = __float2half(acc[m][3]);
            *(uint2*)(Out + (size_t)gr * 64 + ct) = pk.u;
        }
    }
}

// ------------- edge aggregation core (fp16 payload): one wave per node, 16 edges in flight
// wave = 4 groups x 16 lanes; group g handles edges (beg+g) mod 4, 4 per iteration;
// lane l covers channels 4l..4l+3 (uint2 = 4 halves = 8B per lane, 128B per row).

__device__ __forceinline__ float4 agg_node_h(const __half* __restrict__ Hin,
                                             const int* __restrict__ row_ptr,
                                             const int* __restrict__ col,
                                             const float* __restrict__ dinv,
                                             int i, int lane) {
    int g = lane >> 4;
    int l = lane & 15;
    float di = dinv[i];
    int beg = row_ptr[i], end = row_ptr[i + 1];
    float4 acc = make_float4(0.f, 0.f, 0.f, 0.f);
    if (g == 0) {
        union { uint2 u; __half h[4]; } v;
        v.u = *(const uint2*)(Hin + (size_t)i * 64 + l * 4);
        acc.x = di * __half2float(v.h[0]); acc.y = di * __half2float(v.h[1]);
        acc.z = di * __half2float(v.h[2]); acc.w = di * __half2float(v.h[3]);
    }
    for (int e = beg; e < end; e += 16) {
        float w[4];
        uint2 vv[4];
#pragma unroll
        for (int k = 0; k < 4; ++k) {
            int ie = e + g + 4 * k;
            int s = (ie < end) ? col[ie] : 0;
            w[k] = (ie < end) ? dinv[s] : 0.f;
            vv[k] = *(const uint2*)(Hin + (size_t)s * 64 + l * 4);
        }
#pragma unroll
        for (int k = 0; k < 4; ++k) {
            union { uint2 u; __half h[4]; } v;
            v.u = vv[k];
            acc.x = fmaf(w[k], __half2float(v.h[0]), acc.x);
            acc.y = fmaf(w[k], __half2float(v.h[1]), acc.y);
            acc.z = fmaf(w[k], __half2float(v.h[2]), acc.z);
            acc.w = fmaf(w[k], __half2float(v.h[3]), acc.w);
        }
    }
    acc.x += __shfl_xor(acc.x, 16); acc.y += __shfl_xor(acc.y, 16);
    acc.z += __shfl_xor(acc.z, 16); acc.w += __shfl_xor(acc.w, 16);
    acc.x += __shfl_xor(acc.x, 32); acc.y += __shfl_xor(acc.y, 32);
    acc.z += __shfl_xor(acc.z, 32); acc.w += __shfl_xor(acc.w, 32);
    acc.x *= di; acc.y *= di; acc.z *= di; acc.w *= di;
    return acc;
}

// layer 1: h = relu(agg(h0) + b0), fp16 in, fp16 out
__global__ void agg_relu_kernel(const __half* __restrict__ Hin, const int* __restrict__ row_ptr,
                                const int* __restrict__ col, const float* __restrict__ dinv,
                                const float* __restrict__ bias, __half* __restrict__ Hout, int N) {
    int wid = (blockIdx.x * blockDim.x + threadIdx.x) >> 6;
    if (wid >= N) return;
    int lane = threadIdx.x & 63;
    float4 r = agg_node_h(Hin, row_ptr, col, dinv, wid, lane);
    if (lane < 16) {
        float4 b = *(const float4*)(bias + lane * 4);
        union { uint2 u; __half h[4]; } pk;
        pk.h[0] = __float2half(fmaxf(r.x + b.x, 0.f));
        pk.h[1] = __float2half(fmaxf(r.y + b.y, 0.f));
        pk.h[2] = __float2half(fmaxf(r.z + b.z, 0.f));
        pk.h[3] = __float2half(fmaxf(r.w + b.w, 0.f));
        *(uint2*)(Hout + (size_t)wid * 64 + lane * 4) = pk.u;
    }
}

// layer 2 FUSED: g = agg(h); out = [ g@Wm + bm | g@Wl + bl ]  (agg(h@W) == agg(h)@W)
__global__ __launch_bounds__(256) void agg_out_fused_kernel(
        const __half* __restrict__ Hin, const int* __restrict__ row_ptr,
        const int* __restrict__ col, const float* __restrict__ dinv,
        const float* __restrict__ Wm, const float* __restrict__ Wl,
        const float* __restrict__ bm, const float* __restrict__ bl,
        float* __restrict__ out, int N) {
    __shared__ float Ws[64][64];
    int t = threadIdx.x;
    for (int i = t * 4; i < 64 * 32; i += 1024) {
        int k = i >> 5, c = i & 31;
        *(float4*)&Ws[k][c]      = *(const float4*)(Wm + i);
        *(float4*)&Ws[k][32 + c] = *(const float4*)(Wl + i);
    }
    __syncthreads();

    int lane = t & 63;
    float bj = (lane < 32) ? bm[lane] : bl[lane - 32];

    int gw = (blockIdx.x * blockDim.x + t) >> 6;
    int TW = (gridDim.x * blockDim.x) >> 6;
    for (int i = gw; i < N; i += TW) {
        float4 r = agg_node_h(Hin, row_ptr, col, dinv, i, lane);
        float a[4] = {r.x, r.y, r.z, r.w};
        float o = bj;
#pragma unroll
        for (int k = 0; k < 64; ++k) {
            float gk = __shfl(a[k & 3], k >> 2, 64);
            o = fmaf(gk, Ws[k][lane], o);
        }
        if (lane < 32) out[(size_t)i * 32 + lane] = o;
        else           out[(size_t)(N + i) * 32 + (lane - 32)] = o;
    }
}

// ---------------- launch ----------------

extern "C" void kernel_launch(void* const* d_in, const int* in_sizes, int n_in,
                              void* d_out, int out_size, void* d_ws, size_t ws_size,
                              hipStream_t stream) {
    const float* x  = (const float*)d_in[0];
    const int*   ei = (const int*)d_in[1];   // int32 (JAX default int)
    const float* W0 = (const float*)d_in[2];
    const float* b0 = (const float*)d_in[3];
    const float* Wm = (const float*)d_in[4];
    const float* bm = (const float*)d_in[5];
    const float* Wl = (const float*)d_in[6];
    const float* bl = (const float*)d_in[7];
    float* out = (float*)d_out;

    int N = in_sizes[0] / 128;
    int E = in_sizes[1] / 2;
    const int* src = ei;
    const int* dst = ei + E;

    char* p = (char*)d_ws;
    auto carve = [&](size_t bytes) -> void* {
        void* q = (void*)p;
        p += (bytes + 255) & ~(size_t)255;
        return q;
    };
    int*    count    = (int*)carve((size_t)N * 4);          // reused as fill
    int*    row_ptr  = (int*)carve(((size_t)N + 1) * 4);
    int*    col      = (int*)carve((size_t)E * 4);
    float*  dinv     = (float*)carve((size_t)N * 4);
    int*    partials = (int*)carve(128 * 4);
    __half* h0       = (__half*)carve((size_t)N * 64 * 2);  // x@W0 (fp16)
    __half* h        = (__half*)carve((size_t)N * 64 * 2);  // relu'd hidden (fp16)

    int nb = (N + 1023) / 1024;  // scan blocks (<=128 for N<=131072)

    hipMemsetAsync(count, 0, (size_t)N * 4, stream);
    hist_kernel<<<2048, 256, 0, stream>>>(dst, E, count);
    scan_partial_kernel<<<nb, 256, 0, stream>>>(count, partials, N);
    scan_top_kernel<<<1, 128, 0, stream>>>(partials, nb, row_ptr, N);
    scan_apply_kernel<<<nb, 256, 0, stream>>>(count, partials, row_ptr, dinv, N);
    hipMemsetAsync(count, 0, (size_t)N * 4, stream);
    scatter_kernel<<<2048, 256, 0, stream>>>(src, dst, E, row_ptr, count, col);

    // layer 0: h0 = x @ W0 ; h = relu(agg(h0) + b0)
    gemm_kernel<<<(N + 63) / 64, 256, 0, stream>>>(x, W0, h0, N);
    agg_relu_kernel<<<(N + 3) / 4, 256, 0, stream>>>(h0, row_ptr, col, dinv, b0, h, N);

    // layer 2 fused: out = [agg(h)@Wm + bm | agg(h)@Wl + bl]
    agg_out_fused_kernel<<<2048, 256, 0, stream>>>(h, row_ptr, col, dinv, Wm, Wl, bm, bl, out, N);
}

// Round 7
// 355.673 us; speedup vs baseline: 2.0625x; 1.0307x over previous
//
#include <hip/hip_runtime.h>
#include <hip/hip_fp16.h>

// ---------------- preprocessing: degree histogram, 3-phase scan (+dinv), CSR scatter ----

__global__ void hist_kernel(const int* __restrict__ dst, int E, int* __restrict__ count) {
    int stride = gridDim.x * blockDim.x;
    int t = blockIdx.x * blockDim.x + threadIdx.x;
    int E4 = E >> 2;
    for (int e = t; e < E4; e += stride) {
        int4 d = ((const int4*)dst)[e];
        atomicAdd(&count[d.x], 1);
        atomicAdd(&count[d.y], 1);
        atomicAdd(&count[d.z], 1);
        atomicAdd(&count[d.w], 1);
    }
    for (int e = (E4 << 2) + t; e < E; e += stride) atomicAdd(&count[dst[e]], 1);
}

// phase 1: per-block (1024 counts) partial sums
__global__ void scan_partial_kernel(const int* __restrict__ count, int* __restrict__ partials,
                                    int N) {
    __shared__ int red[4];
    int t = threadIdx.x;
    int idx = blockIdx.x * 1024 + t * 4;
    int s = 0;
    if (idx + 3 < N) {
        int4 c = *(const int4*)(count + idx);
        s = c.x + c.y + c.z + c.w;
    } else {
#pragma unroll
        for (int k = 0; k < 4; ++k)
            if (idx + k < N) s += count[idx + k];
    }
#pragma unroll
    for (int off = 1; off < 64; off <<= 1) s += __shfl_xor(s, off);
    if ((t & 63) == 0) red[t >> 6] = s;
    __syncthreads();
    if (t == 0) partials[blockIdx.x] = red[0] + red[1] + red[2] + red[3];
}

// phase 2: exclusive scan of the (<=128) partials; also writes row_ptr[N] = total
__global__ void scan_top_kernel(int* __restrict__ partials, int nb, int* __restrict__ row_ptr,
                                int N) {
    __shared__ int buf[2][128];
    int t = threadIdx.x;
    buf[0][t] = (t < nb) ? partials[t] : 0;
    __syncthreads();
    int pi = 0;
    for (int off = 1; off < 128; off <<= 1) {
        int v = buf[pi][t];
        if (t >= off) v += buf[pi][t - off];
        buf[pi ^ 1][t] = v;
        pi ^= 1;
        __syncthreads();
    }
    if (t < nb) partials[t] = (t == 0) ? 0 : buf[pi][t - 1];
    if (t == 0) row_ptr[N] = buf[pi][127];
}

// phase 3: in-block exclusive scan + block offset -> row_ptr; dinv fused
__global__ void scan_apply_kernel(const int* __restrict__ count, const int* __restrict__ partials,
                                  int* __restrict__ row_ptr, float* __restrict__ dinv, int N) {
    __shared__ int wsum[4];
    int t = threadIdx.x;
    int idx = blockIdx.x * 1024 + t * 4;
    int4 c = make_int4(0, 0, 0, 0);
    if (idx + 3 < N) {
        c = *(const int4*)(count + idx);
    } else {
        if (idx + 0 < N) c.x = count[idx + 0];
        if (idx + 1 < N) c.y = count[idx + 1];
        if (idx + 2 < N) c.z = count[idx + 2];
    }
    int s = c.x + c.y + c.z + c.w;
    int incl = s;
#pragma unroll
    for (int off = 1; off < 64; off <<= 1) {
        int v = __shfl_up(incl, off);
        if ((t & 63) >= off) incl += v;
    }
    int wexcl = incl - s;
    int w = t >> 6;
    if ((t & 63) == 63) wsum[w] = incl;
    __syncthreads();
    int base = partials[blockIdx.x] + wexcl;
    for (int k = 0; k < w; ++k) base += wsum[k];
    if (idx + 0 < N) { row_ptr[idx + 0] = base;                   dinv[idx + 0] = rsqrtf((float)c.x + 1.f); }
    if (idx + 1 < N) { row_ptr[idx + 1] = base + c.x;             dinv[idx + 1] = rsqrtf((float)c.y + 1.f); }
    if (idx + 2 < N) { row_ptr[idx + 2] = base + c.x + c.y;       dinv[idx + 2] = rsqrtf((float)c.z + 1.f); }
    if (idx + 3 < N) { row_ptr[idx + 3] = base + c.x + c.y + c.z; dinv[idx + 3] = rsqrtf((float)c.w + 1.f); }
}

__global__ void scatter_kernel(const int* __restrict__ src, const int* __restrict__ dst, int E,
                               const int* __restrict__ row_ptr, int* __restrict__ fill,
                               int* __restrict__ col) {
    int stride = gridDim.x * blockDim.x;
    int t = blockIdx.x * blockDim.x + threadIdx.x;
    int E4 = E >> 2;
    for (int e = t; e < E4; e += stride) {
        int4 s = ((const int4*)src)[e];
        int4 d = ((const int4*)dst)[e];
        col[row_ptr[d.x] + atomicAdd(&fill[d.x], 1)] = s.x;
        col[row_ptr[d.y] + atomicAdd(&fill[d.y], 1)] = s.y;
        col[row_ptr[d.z] + atomicAdd(&fill[d.z], 1)] = s.z;
        col[row_ptr[d.w] + atomicAdd(&fill[d.w], 1)] = s.w;
    }
    for (int e = (E4 << 2) + t; e < E; e += stride) {
        int d = dst[e];
        col[row_ptr[d] + atomicAdd(&fill[d], 1)] = src[e];
    }
}

// -------- fp32 GEMM, PRE-SCALED fp16 output: Out[r] = dinv[r] * (A @ W)[r] --------------

__global__ __launch_bounds__(256, 2) void gemm_kernel(const float* __restrict__ A,
                                                      const float* __restrict__ W,
                                                      const float* __restrict__ dinv,
                                                      __half* __restrict__ Out, int M) {
    const int K = 128;
    __shared__ float Ws[K][64];
    __shared__ float As[64][68];
    int t = threadIdx.x;
    for (int i = t * 4; i < K * 64; i += 1024)
        *(float4*)&Ws[i >> 6][i & 63] = *(const float4*)(W + i);

    int row0 = blockIdx.x * 64;
    int rt = (t >> 4) * 4;
    int ct = (t & 15) * 4;
    float acc[4][4];
#pragma unroll
    for (int m = 0; m < 4; m++) { acc[m][0] = 0.f; acc[m][1] = 0.f; acc[m][2] = 0.f; acc[m][3] = 0.f; }

    for (int k0 = 0; k0 < K; k0 += 64) {
        __syncthreads();
        for (int i = t * 4; i < 64 * 64; i += 1024) {
            int r = i >> 6, c = i & 63;
            int gr = row0 + r;
            float4 v = make_float4(0.f, 0.f, 0.f, 0.f);
            if (gr < M) v = *(const float4*)(A + (size_t)gr * K + k0 + c);
            *(float4*)&As[r][c] = v;
        }
        __syncthreads();
#pragma unroll
        for (int kk = 0; kk < 64; ++kk) {
            float a0 = As[rt + 0][kk], a1 = As[rt + 1][kk];
            float a2 = As[rt + 2][kk], a3 = As[rt + 3][kk];
            float4 w = *(float4*)&Ws[k0 + kk][ct];
            acc[0][0] += a0 * w.x; acc[0][1] += a0 * w.y; acc[0][2] += a0 * w.z; acc[0][3] += a0 * w.w;
            acc[1][0] += a1 * w.x; acc[1][1] += a1 * w.y; acc[1][2] += a1 * w.z; acc[1][3] += a1 * w.w;
            acc[2][0] += a2 * w.x; acc[2][1] += a2 * w.y; acc[2][2] += a2 * w.z; acc[2][3] += a2 * w.w;
            acc[3][0] += a3 * w.x; acc[3][1] += a3 * w.y; acc[3][2] += a3 * w.z; acc[3][3] += a3 * w.w;
        }
    }
#pragma unroll
    for (int m = 0; m < 4; m++) {
        int gr = row0 + rt + m;
        if (gr < M) {
            float dv = dinv[gr];
            union { uint2 u; __half h[4]; } pk;
            pk.h[0] = __float2half(dv * acc[m][0]);
            pk.h[1] = __float2half(dv * acc[m][1]);
            pk.h[2] = __float2half(dv * acc[m][2]);
            pk.h[3] = __float2half(dv * acc[m][3]);
            *(uint2*)(Out + (size_t)gr * 64 + ct) = pk.u;
        }
    }
}

// -------- edge aggregation core (pre-scaled fp16 payload): plain-sum gather --------------
// Hin holds h' = dinv_j * h_j, so  result = di * ( sum_{e} h'[col[e]] + h'[i] ).
// wave = 4 groups x 16 lanes; group g handles edges (beg+g) mod 4, 4 per round;
// lane l covers channels 4l..4l+3 (uint2 = 4 halves = 8B/lane, 128B/row).
// Per-edge chain is now col -> row only (no dinv gather).

__device__ __forceinline__ float4 agg_node_h(const __half* __restrict__ Hin,
                                             const int* __restrict__ row_ptr,
                                             const int* __restrict__ col,
                                             float di, int i, int lane) {
    int g = lane >> 4;
    int l = lane & 15;
    int beg = row_ptr[i], end = row_ptr[i + 1];
    float4 acc = make_float4(0.f, 0.f, 0.f, 0.f);
    if (g == 0) {  // self-loop: di*h_i == h'_i (unscaled here; final *di below)
        union { uint2 u; __half h[4]; } v;
        v.u = *(const uint2*)(Hin + (size_t)i * 64 + l * 4);
        acc.x = __half2float(v.h[0]); acc.y = __half2float(v.h[1]);
        acc.z = __half2float(v.h[2]); acc.w = __half2float(v.h[3]);
    }
    int deg = end - beg;
    int e = beg;
    int efull = beg + ((deg >> 4) << 4);
    for (; e < efull; e += 16) {  // full rounds: no predication
        int s[4];
#pragma unroll
        for (int k = 0; k < 4; ++k) s[k] = col[e + g + 4 * k];
        uint2 vv[4];
#pragma unroll
        for (int k = 0; k < 4; ++k) vv[k] = *(const uint2*)(Hin + (size_t)s[k] * 64 + l * 4);
#pragma unroll
        for (int k = 0; k < 4; ++k) {
            union { uint2 u; __half h[4]; } v;
            v.u = vv[k];
            acc.x += __half2float(v.h[0]); acc.y += __half2float(v.h[1]);
            acc.z += __half2float(v.h[2]); acc.w += __half2float(v.h[3]);
        }
    }
    if (e < end) {  // tail round: predicated by zero-weight
        float w[4];
        uint2 vv[4];
#pragma unroll
        for (int k = 0; k < 4; ++k) {
            int ie = e + g + 4 * k;
            int s = (ie < end) ? col[ie] : 0;
            w[k] = (ie < end) ? 1.f : 0.f;
            vv[k] = *(const uint2*)(Hin + (size_t)s * 64 + l * 4);
        }
#pragma unroll
        for (int k = 0; k < 4; ++k) {
            union { uint2 u; __half h[4]; } v;
            v.u = vv[k];
            acc.x = fmaf(w[k], __half2float(v.h[0]), acc.x);
            acc.y = fmaf(w[k], __half2float(v.h[1]), acc.y);
            acc.z = fmaf(w[k], __half2float(v.h[2]), acc.z);
            acc.w = fmaf(w[k], __half2float(v.h[3]), acc.w);
        }
    }
    acc.x += __shfl_xor(acc.x, 16); acc.y += __shfl_xor(acc.y, 16);
    acc.z += __shfl_xor(acc.z, 16); acc.w += __shfl_xor(acc.w, 16);
    acc.x += __shfl_xor(acc.x, 32); acc.y += __shfl_xor(acc.y, 32);
    acc.z += __shfl_xor(acc.z, 32); acc.w += __shfl_xor(acc.w, 32);
    acc.x *= di; acc.y *= di; acc.z *= di; acc.w *= di;
    return acc;
}

// layer 1: t = relu(agg + b0); store pre-scaled h' = dinv_i * t   (fp16)
__global__ void agg_relu_kernel(const __half* __restrict__ Hin, const int* __restrict__ row_ptr,
                                const int* __restrict__ col, const float* __restrict__ dinv,
                                const float* __restrict__ bias, __half* __restrict__ Hout, int N) {
    int wid = (blockIdx.x * blockDim.x + threadIdx.x) >> 6;
    if (wid >= N) return;
    int lane = threadIdx.x & 63;
    float di = dinv[wid];
    float4 r = agg_node_h(Hin, row_ptr, col, di, wid, lane);
    if (lane < 16) {
        float4 b = *(const float4*)(bias + lane * 4);
        union { uint2 u; __half h[4]; } pk;
        pk.h[0] = __float2half(di * fmaxf(r.x + b.x, 0.f));
        pk.h[1] = __float2half(di * fmaxf(r.y + b.y, 0.f));
        pk.h[2] = __float2half(di * fmaxf(r.z + b.z, 0.f));
        pk.h[3] = __float2half(di * fmaxf(r.w + b.w, 0.f));
        *(uint2*)(Hout + (size_t)wid * 64 + lane * 4) = pk.u;
    }
}

// layer 2 FUSED: g = agg(h); out = [ g@Wm + bm | g@Wl + bl ]  (agg(h@W) == agg(h)@W)
__global__ __launch_bounds__(256) void agg_out_fused_kernel(
        const __half* __restrict__ Hin, const int* __restrict__ row_ptr,
        const int* __restrict__ col, const float* __restrict__ dinv,
        const float* __restrict__ Wm, const float* __restrict__ Wl,
        const float* __restrict__ bm, const float* __restrict__ bl,
        float* __restrict__ out, int N) {
    __shared__ float Ws[64][64];
    int t = threadIdx.x;
    for (int i = t * 4; i < 64 * 32; i += 1024) {
        int k = i >> 5, c = i & 31;
        *(float4*)&Ws[k][c]      = *(const float4*)(Wm + i);
        *(float4*)&Ws[k][32 + c] = *(const float4*)(Wl + i);
    }
    __syncthreads();

    int lane = t & 63;
    float bj = (lane < 32) ? bm[lane] : bl[lane - 32];

    int gw = (blockIdx.x * blockDim.x + t) >> 6;
    int TW = (gridDim.x * blockDim.x) >> 6;
    for (int i = gw; i < N; i += TW) {
        float4 r = agg_node_h(Hin, row_ptr, col, dinv[i], i, lane);
        float a[4] = {r.x, r.y, r.z, r.w};
        float o = bj;
#pragma unroll
        for (int k = 0; k < 64; ++k) {
            float gk = __shfl(a[k & 3], k >> 2, 64);
            o = fmaf(gk, Ws[k][lane], o);
        }
        if (lane < 32) out[(size_t)i * 32 + lane] = o;
        else           out[(size_t)(N + i) * 32 + (lane - 32)] = o;
    }
}

// ---------------- launch ----------------

extern "C" void kernel_launch(void* const* d_in, const int* in_sizes, int n_in,
                              void* d_out, int out_size, void* d_ws, size_t ws_size,
                              hipStream_t stream) {
    const float* x  = (const float*)d_in[0];
    const int*   ei = (const int*)d_in[1];   // int32 (JAX default int)
    const float* W0 = (const float*)d_in[2];
    const float* b0 = (const float*)d_in[3];
    const float* Wm = (const float*)d_in[4];
    const float* bm = (const float*)d_in[5];
    const float* Wl = (const float*)d_in[6];
    const float* bl = (const float*)d_in[7];
    float* out = (float*)d_out;

    int N = in_sizes[0] / 128;
    int E = in_sizes[1] / 2;
    const int* src = ei;
    const int* dst = ei + E;

    char* p = (char*)d_ws;
    auto carve = [&](size_t bytes) -> void* {
        void* q = (void*)p;
        p += (bytes + 255) & ~(size_t)255;
        return q;
    };
    int*    count    = (int*)carve((size_t)N * 4);          // reused as fill
    int*    row_ptr  = (int*)carve(((size_t)N + 1) * 4);
    int*    col      = (int*)carve((size_t)E * 4);
    float*  dinv     = (float*)carve((size_t)N * 4);
    int*    partials = (int*)carve(128 * 4);
    __half* h0       = (__half*)carve((size_t)N * 64 * 2);  // dinv*(x@W0) (fp16)
    __half* h        = (__half*)carve((size_t)N * 64 * 2);  // dinv*relu'd hidden (fp16)

    int nb = (N + 1023) / 1024;  // scan blocks (<=128 for N<=131072)

    hipMemsetAsync(count, 0, (size_t)N * 4, stream);
    hist_kernel<<<2048, 256, 0, stream>>>(dst, E, count);
    scan_partial_kernel<<<nb, 256, 0, stream>>>(count, partials, N);
    scan_top_kernel<<<1, 128, 0, stream>>>(partials, nb, row_ptr, N);
    scan_apply_kernel<<<nb, 256, 0, stream>>>(count, partials, row_ptr, dinv, N);
    hipMemsetAsync(count, 0, (size_t)N * 4, stream);
    scatter_kernel<<<2048, 256, 0, stream>>>(src, dst, E, row_ptr, count, col);

    // layer 0: h0' = dinv * (x @ W0) ; h' = dinv * relu(agg(h0') + b0)
    gemm_kernel<<<(N + 63) / 64, 256, 0, stream>>>(x, W0, dinv, h0, N);
    agg_relu_kernel<<<(N + 3) / 4, 256, 0, stream>>>(h0, row_ptr, col, dinv, b0, h, N);

    // layer 2 fused: out = [agg(h')@Wm + bm | agg(h')@Wl + bl]
    agg_out_fused_kernel<<<2048, 256, 0, stream>>>(h, row_ptr, col, dinv, Wm, Wl, bm, bl, out, N);
}

// Round 8
// 281.530 us; speedup vs baseline: 2.6056x; 1.2634x over previous
//
#include <hip/hip_runtime.h>
#include <hip/hip_fp16.h>

// ---------------- preprocessing: histogram+rank, 3-phase scan (+dinv), passed scatter ----

// rank[e] = arrival order of edge e at its dst; count[d] = degree of d
__global__ void hist_rank_kernel(const int* __restrict__ dst, int E, int* __restrict__ count,
                                 int* __restrict__ rank) {
    int stride = gridDim.x * blockDim.x;
    int t = blockIdx.x * blockDim.x + threadIdx.x;
    int E4 = E >> 2;
    for (int e = t; e < E4; e += stride) {
        int4 d = ((const int4*)dst)[e];
        int4 r;
        r.x = atomicAdd(&count[d.x], 1);
        r.y = atomicAdd(&count[d.y], 1);
        r.z = atomicAdd(&count[d.z], 1);
        r.w = atomicAdd(&count[d.w], 1);
        ((int4*)rank)[e] = r;
    }
    for (int e = (E4 << 2) + t; e < E; e += stride) rank[e] = atomicAdd(&count[dst[e]], 1);
}

// phase 1: per-block (1024 counts) partial sums
__global__ void scan_partial_kernel(const int* __restrict__ count, int* __restrict__ partials,
                                    int N) {
    __shared__ int red[4];
    int t = threadIdx.x;
    int idx = blockIdx.x * 1024 + t * 4;
    int s = 0;
    if (idx + 3 < N) {
        int4 c = *(const int4*)(count + idx);
        s = c.x + c.y + c.z + c.w;
    } else {
#pragma unroll
        for (int k = 0; k < 4; ++k)
            if (idx + k < N) s += count[idx + k];
    }
#pragma unroll
    for (int off = 1; off < 64; off <<= 1) s += __shfl_xor(s, off);
    if ((t & 63) == 0) red[t >> 6] = s;
    __syncthreads();
    if (t == 0) partials[blockIdx.x] = red[0] + red[1] + red[2] + red[3];
}

// phase 2: exclusive scan of the (<=128) partials; also writes row_ptr[N] = total
__global__ void scan_top_kernel(int* __restrict__ partials, int nb, int* __restrict__ row_ptr,
                                int N) {
    __shared__ int buf[2][128];
    int t = threadIdx.x;
    buf[0][t] = (t < nb) ? partials[t] : 0;
    __syncthreads();
    int pi = 0;
    for (int off = 1; off < 128; off <<= 1) {
        int v = buf[pi][t];
        if (t >= off) v += buf[pi][t - off];
        buf[pi ^ 1][t] = v;
        pi ^= 1;
        __syncthreads();
    }
    if (t < nb) partials[t] = (t == 0) ? 0 : buf[pi][t - 1];
    if (t == 0) row_ptr[N] = buf[pi][127];
}

// phase 3: in-block exclusive scan + block offset -> row_ptr; dinv fused
__global__ void scan_apply_kernel(const int* __restrict__ count, const int* __restrict__ partials,
                                  int* __restrict__ row_ptr, float* __restrict__ dinv, int N) {
    __shared__ int wsum[4];
    int t = threadIdx.x;
    int idx = blockIdx.x * 1024 + t * 4;
    int4 c = make_int4(0, 0, 0, 0);
    if (idx + 3 < N) {
        c = *(const int4*)(count + idx);
    } else {
        if (idx + 0 < N) c.x = count[idx + 0];
        if (idx + 1 < N) c.y = count[idx + 1];
        if (idx + 2 < N) c.z = count[idx + 2];
    }
    int s = c.x + c.y + c.z + c.w;
    int incl = s;
#pragma unroll
    for (int off = 1; off < 64; off <<= 1) {
        int v = __shfl_up(incl, off);
        if ((t & 63) >= off) incl += v;
    }
    int wexcl = incl - s;
    int w = t >> 6;
    if ((t & 63) == 63) wsum[w] = incl;
    __syncthreads();
    int base = partials[blockIdx.x] + wexcl;
    for (int k = 0; k < w; ++k) base += wsum[k];
    if (idx + 0 < N) { row_ptr[idx + 0] = base;                   dinv[idx + 0] = rsqrtf((float)c.x + 1.f); }
    if (idx + 1 < N) { row_ptr[idx + 1] = base + c.x;             dinv[idx + 1] = rsqrtf((float)c.y + 1.f); }
    if (idx + 2 < N) { row_ptr[idx + 2] = base + c.x + c.y;       dinv[idx + 2] = rsqrtf((float)c.z + 1.f); }
    if (idx + 3 < N) { row_ptr[idx + 3] = base + c.x + c.y + c.z; dinv[idx + 3] = rsqrtf((float)c.w + 1.f); }
}

// atomic-free scatter with dst-range write blocking: pass p writes only col entries for
// dst in [p*chunk,(p+1)*chunk) -> ~(E/NPASS)*4B contiguous col window, full-line writebacks.
// Edge-list re-reads are L3-resident (FETCH counter showed 8MB for 12.8MB of inputs).
#define NPASS 8
__global__ void scatter_kernel(const int* __restrict__ src, const int* __restrict__ dst,
                               const int* __restrict__ rank, int E,
                               const int* __restrict__ row_ptr, int* __restrict__ col, int N) {
    int chunk = (N + NPASS - 1) / NPASS;
    int stride = gridDim.x * blockDim.x;
    int t = blockIdx.x * blockDim.x + threadIdx.x;
    int E4 = E >> 2;
    for (int pass = 0; pass < NPASS; ++pass) {
        int lo = pass * chunk, hi = min(lo + chunk, N);
        for (int e = t; e < E4; e += stride) {
            int4 d = ((const int4*)dst)[e];
            int4 s = ((const int4*)src)[e];
            int4 r = ((const int4*)rank)[e];
            if (d.x >= lo && d.x < hi) col[row_ptr[d.x] + r.x] = s.x;
            if (d.y >= lo && d.y < hi) col[row_ptr[d.y] + r.y] = s.y;
            if (d.z >= lo && d.z < hi) col[row_ptr[d.z] + r.z] = s.z;
            if (d.w >= lo && d.w < hi) col[row_ptr[d.w] + r.w] = s.w;
        }
        for (int e = (E4 << 2) + t; e < E; e += stride) {
            int d = dst[e];
            if (d >= lo && d < hi) col[row_ptr[d] + rank[e]] = src[e];
        }
    }
}

// -------- fp32 GEMM, PRE-SCALED fp16 output: Out[r] = dinv[r] * (A @ W)[r] --------------

__global__ __launch_bounds__(256, 2) void gemm_kernel(const float* __restrict__ A,
                                                      const float* __restrict__ W,
                                                      const float* __restrict__ dinv,
                                                      __half* __restrict__ Out, int M) {
    const int K = 128;
    __shared__ float Ws[K][64];
    __shared__ float As[64][68];
    int t = threadIdx.x;
    for (int i = t * 4; i < K * 64; i += 1024)
        *(float4*)&Ws[i >> 6][i & 63] = *(const float4*)(W + i);

    int row0 = blockIdx.x * 64;
    int rt = (t >> 4) * 4;
    int ct = (t & 15) * 4;
    float acc[4][4];
#pragma unroll
    for (int m = 0; m < 4; m++) { acc[m][0] = 0.f; acc[m][1] = 0.f; acc[m][2] = 0.f; acc[m][3] = 0.f; }

    for (int k0 = 0; k0 < K; k0 += 64) {
        __syncthreads();
        for (int i = t * 4; i < 64 * 64; i += 1024) {
            int r = i >> 6, c = i & 63;
            int gr = row0 + r;
            float4 v = make_float4(0.f, 0.f, 0.f, 0.f);
            if (gr < M) v = *(const float4*)(A + (size_t)gr * K + k0 + c);
            *(float4*)&As[r][c] = v;
        }
        __syncthreads();
#pragma unroll
        for (int kk = 0; kk < 64; ++kk) {
            float a0 = As[rt + 0][kk], a1 = As[rt + 1][kk];
            float a2 = As[rt + 2][kk], a3 = As[rt + 3][kk];
            float4 w = *(float4*)&Ws[k0 + kk][ct];
            acc[0][0] += a0 * w.x; acc[0][1] += a0 * w.y; acc[0][2] += a0 * w.z; acc[0][3] += a0 * w.w;
            acc[1][0] += a1 * w.x; acc[1][1] += a1 * w.y; acc[1][2] += a1 * w.z; acc[1][3] += a1 * w.w;
            acc[2][0] += a2 * w.x; acc[2][1] += a2 * w.y; acc[2][2] += a2 * w.z; acc[2][3] += a2 * w.w;
            acc[3][0] += a3 * w.x; acc[3][1] += a3 * w.y; acc[3][2] += a3 * w.z; acc[3][3] += a3 * w.w;
        }
    }
#pragma unroll
    for (int m = 0; m < 4; m++) {
        int gr = row0 + rt + m;
        if (gr < M) {
            float dv = dinv[gr];
            union { uint2 u; __half h[4]; } pk;
            pk.h[0] = __float2half(dv * acc[m][0]);
            pk.h[1] = __float2half(dv * acc[m][1]);
            pk.h[2] = __float2half(dv * acc[m][2]);
            pk.h[3] = __float2half(dv * acc[m][3]);
            *(uint2*)(Out + (size_t)gr * 64 + ct) = pk.u;
        }
    }
}

// -------- edge aggregation core (pre-scaled fp16 payload): plain-sum gather --------------

__device__ __forceinline__ float4 agg_node_h(const __half* __restrict__ Hin,
                                             const int* __restrict__ row_ptr,
                                             const int* __restrict__ col,
                                             float di, int i, int lane) {
    int g = lane >> 4;
    int l = lane & 15;
    int beg = row_ptr[i], end = row_ptr[i + 1];
    float4 acc = make_float4(0.f, 0.f, 0.f, 0.f);
    if (g == 0) {  // self-loop: di*h_i == h'_i (unscaled here; final *di below)
        union { uint2 u; __half h[4]; } v;
        v.u = *(const uint2*)(Hin + (size_t)i * 64 + l * 4);
        acc.x = __half2float(v.h[0]); acc.y = __half2float(v.h[1]);
        acc.z = __half2float(v.h[2]); acc.w = __half2float(v.h[3]);
    }
    int deg = end - beg;
    int e = beg;
    int efull = beg + ((deg >> 4) << 4);
    for (; e < efull; e += 16) {  // full rounds: no predication
        int s[4];
#pragma unroll
        for (int k = 0; k < 4; ++k) s[k] = col[e + g + 4 * k];
        uint2 vv[4];
#pragma unroll
        for (int k = 0; k < 4; ++k) vv[k] = *(const uint2*)(Hin + (size_t)s[k] * 64 + l * 4);
#pragma unroll
        for (int k = 0; k < 4; ++k) {
            union { uint2 u; __half h[4]; } v;
            v.u = vv[k];
            acc.x += __half2float(v.h[0]); acc.y += __half2float(v.h[1]);
            acc.z += __half2float(v.h[2]); acc.w += __half2float(v.h[3]);
        }
    }
    if (e < end) {  // tail round: predicated by zero-weight
        float w[4];
        uint2 vv[4];
#pragma unroll
        for (int k = 0; k < 4; ++k) {
            int ie = e + g + 4 * k;
            int s = (ie < end) ? col[ie] : 0;
            w[k] = (ie < end) ? 1.f : 0.f;
            vv[k] = *(const uint2*)(Hin + (size_t)s * 64 + l * 4);
        }
#pragma unroll
        for (int k = 0; k < 4; ++k) {
            union { uint2 u; __half h[4]; } v;
            v.u = vv[k];
            acc.x = fmaf(w[k], __half2float(v.h[0]), acc.x);
            acc.y = fmaf(w[k], __half2float(v.h[1]), acc.y);
            acc.z = fmaf(w[k], __half2float(v.h[2]), acc.z);
            acc.w = fmaf(w[k], __half2float(v.h[3]), acc.w);
        }
    }
    acc.x += __shfl_xor(acc.x, 16); acc.y += __shfl_xor(acc.y, 16);
    acc.z += __shfl_xor(acc.z, 16); acc.w += __shfl_xor(acc.w, 16);
    acc.x += __shfl_xor(acc.x, 32); acc.y += __shfl_xor(acc.y, 32);
    acc.z += __shfl_xor(acc.z, 32); acc.w += __shfl_xor(acc.w, 32);
    acc.x *= di; acc.y *= di; acc.z *= di; acc.w *= di;
    return acc;
}

// layer 1: t = relu(agg + b0); store pre-scaled h' = dinv_i * t   (fp16)
__global__ void agg_relu_kernel(const __half* __restrict__ Hin, const int* __restrict__ row_ptr,
                                const int* __restrict__ col, const float* __restrict__ dinv,
                                const float* __restrict__ bias, __half* __restrict__ Hout, int N) {
    int wid = (blockIdx.x * blockDim.x + threadIdx.x) >> 6;
    if (wid >= N) return;
    int lane = threadIdx.x & 63;
    float di = dinv[wid];
    float4 r = agg_node_h(Hin, row_ptr, col, di, wid, lane);
    if (lane < 16) {
        float4 b = *(const float4*)(bias + lane * 4);
        union { uint2 u; __half h[4]; } pk;
        pk.h[0] = __float2half(di * fmaxf(r.x + b.x, 0.f));
        pk.h[1] = __float2half(di * fmaxf(r.y + b.y, 0.f));
        pk.h[2] = __float2half(di * fmaxf(r.z + b.z, 0.f));
        pk.h[3] = __float2half(di * fmaxf(r.w + b.w, 0.f));
        *(uint2*)(Hout + (size_t)wid * 64 + lane * 4) = pk.u;
    }
}

// layer 2 FUSED: g = agg(h); out = [ g@Wm + bm | g@Wl + bl ]  (agg(h@W) == agg(h)@W)
__global__ __launch_bounds__(256) void agg_out_fused_kernel(
        const __half* __restrict__ Hin, const int* __restrict__ row_ptr,
        const int* __restrict__ col, const float* __restrict__ dinv,
        const float* __restrict__ Wm, const float* __restrict__ Wl,
        const float* __restrict__ bm, const float* __restrict__ bl,
        float* __restrict__ out, int N) {
    __shared__ float Ws[64][64];
    int t = threadIdx.x;
    for (int i = t * 4; i < 64 * 32; i += 1024) {
        int k = i >> 5, c = i & 31;
        *(float4*)&Ws[k][c]      = *(const float4*)(Wm + i);
        *(float4*)&Ws[k][32 + c] = *(const float4*)(Wl + i);
    }
    __syncthreads();

    int lane = t & 63;
    float bj = (lane < 32) ? bm[lane] : bl[lane - 32];

    int gw = (blockIdx.x * blockDim.x + t) >> 6;
    int TW = (gridDim.x * blockDim.x) >> 6;
    for (int i = gw; i < N; i += TW) {
        float4 r = agg_node_h(Hin, row_ptr, col, dinv[i], i, lane);
        float a[4] = {r.x, r.y, r.z, r.w};
        float o = bj;
#pragma unroll
        for (int k = 0; k < 64; ++k) {
            float gk = __shfl(a[k & 3], k >> 2, 64);
            o = fmaf(gk, Ws[k][lane], o);
        }
        if (lane < 32) out[(size_t)i * 32 + lane] = o;
        else           out[(size_t)(N + i) * 32 + (lane - 32)] = o;
    }
}

// ---------------- launch ----------------

extern "C" void kernel_launch(void* const* d_in, const int* in_sizes, int n_in,
                              void* d_out, int out_size, void* d_ws, size_t ws_size,
                              hipStream_t stream) {
    const float* x  = (const float*)d_in[0];
    const int*   ei = (const int*)d_in[1];   // int32 (JAX default int)
    const float* W0 = (const float*)d_in[2];
    const float* b0 = (const float*)d_in[3];
    const float* Wm = (const float*)d_in[4];
    const float* bm = (const float*)d_in[5];
    const float* Wl = (const float*)d_in[6];
    const float* bl = (const float*)d_in[7];
    float* out = (float*)d_out;

    int N = in_sizes[0] / 128;
    int E = in_sizes[1] / 2;
    const int* src = ei;
    const int* dst = ei + E;

    char* p = (char*)d_ws;
    auto carve = [&](size_t bytes) -> void* {
        void* q = (void*)p;
        p += (bytes + 255) & ~(size_t)255;
        return q;
    };
    int*    count    = (int*)carve((size_t)N * 4);
    int*    row_ptr  = (int*)carve(((size_t)N + 1) * 4);
    int*    col      = (int*)carve((size_t)E * 4);
    int*    rank     = (int*)carve((size_t)E * 4);
    float*  dinv     = (float*)carve((size_t)N * 4);
    int*    partials = (int*)carve(128 * 4);
    __half* h0       = (__half*)carve((size_t)N * 64 * 2);  // dinv*(x@W0) (fp16)
    __half* h        = (__half*)carve((size_t)N * 64 * 2);  // dinv*relu'd hidden (fp16)

    int nb = (N + 1023) / 1024;  // scan blocks (<=128 for N<=131072)

    hipMemsetAsync(count, 0, (size_t)N * 4, stream);
    hist_rank_kernel<<<2048, 256, 0, stream>>>(dst, E, count, rank);
    scan_partial_kernel<<<nb, 256, 0, stream>>>(count, partials, N);
    scan_top_kernel<<<1, 128, 0, stream>>>(partials, nb, row_ptr, N);
    scan_apply_kernel<<<nb, 256, 0, stream>>>(count, partials, row_ptr, dinv, N);
    scatter_kernel<<<2048, 256, 0, stream>>>(src, dst, rank, E, row_ptr, col, N);

    // layer 0: h0' = dinv * (x @ W0) ; h' = dinv * relu(agg(h0') + b0)
    gemm_kernel<<<(N + 63) / 64, 256, 0, stream>>>(x, W0, dinv, h0, N);
    agg_relu_kernel<<<(N + 3) / 4, 256, 0, stream>>>(h0, row_ptr, col, dinv, b0, h, N);

    // layer 2 fused: out = [agg(h')@Wm + bm | agg(h')@Wl + bl]
    agg_out_fused_kernel<<<2048, 256, 0, stream>>>(h, row_ptr, col, dinv, Wm, Wl, bm, bl, out, N);
}